// Round 6
// baseline (603.464 us; speedup 1.0000x reference)
//
#include <hip/hip_runtime.h>

// ---------------------------------------------------------------------------
// RGCN restructured: aggregate x[src] FIRST (per relation), then one GEMM
//   A = [Sn_rel0 | Sn_rel1 | x_self],  Wcat = [W0; W1; root]
// R4: CSR build via two-level counting sort (cache-resident random writes).
// R5: k_clf one wave per graph.
// R6: gathers are VALU-issue-bound (VALUBusy 96%) -> rewrite inner loop:
//     per-segment uniform loops (no per-edge relation select = -16 inst),
//     broadcast ssrc loads (no staging+shfl), full packets + guarded tail.
// ---------------------------------------------------------------------------

typedef unsigned int uint;
typedef unsigned short ushort;

#define EPB 8192   // edges per block in count/partition kernels

__device__ __forceinline__ void fma4(float4& a, float s, const float4& w){
  a.x += s*w.x; a.y += s*w.y; a.z += s*w.z; a.w += s*w.w;
}
__device__ __forceinline__ uint bf1(float f){          // f32 -> bf16 (RNE)
  uint u = __float_as_uint(f);
  return (u + 0x7fffu + ((u>>16)&1u)) >> 16;
}
__device__ __forceinline__ uint bfpack2(float lo, float hi){
  return bf1(lo) | (bf1(hi)<<16);
}
__device__ __forceinline__ float2 bf2cvt(uint w){
  float2 r; r.x = __uint_as_float(w<<16); r.y = __uint_as_float(w & 0xffff0000u);
  return r;
}

// --------------------- CSR build: two-level counting sort ------------------

__global__ __launch_bounds__(256) void k_count(const int* __restrict__ ei,
    int* __restrict__ bhist, int E){
  __shared__ int h[256];
  int t = threadIdx.x;
  h[t] = 0; __syncthreads();
  int base = blockIdx.x*EPB;
  for (int i=t; i<EPB; i+=256){
    int e = base+i;
    if (e < E) atomicAdd(&h[ei[E+e]>>9], 1);
  }
  __syncthreads();
  if (h[t]) atomicAdd(&bhist[t], h[t]);
}

__global__ __launch_bounds__(256) void k_bscan(const int* __restrict__ bhist,
    int* __restrict__ bbase, int* __restrict__ bcur){
  __shared__ int lds[256];
  int t = threadIdx.x;
  int v = bhist[t];
  lds[t] = v; __syncthreads();
  for (int off=1; off<256; off<<=1){
    int tmp = (t>=off)? lds[t-off]:0;
    __syncthreads();
    lds[t] += tmp;
    __syncthreads();
  }
  int excl = lds[t]-v;
  bbase[t] = excl; bcur[t] = excl;
  if (t==255) bbase[256] = excl+v;
}

// partition edges into bucket regions as packed (src<<10)|((dst&511)<<1|ty)
__global__ __launch_bounds__(256) void k_part(const int* __restrict__ ei,
    const int* __restrict__ et, int* __restrict__ bcur,
    uint* __restrict__ bk, int E){
  __shared__ int h[256];
  __shared__ int cur[256];
  int t = threadIdx.x;
  h[t] = 0; __syncthreads();
  int base = blockIdx.x*EPB;
  for (int i=t; i<EPB; i+=256){
    int e = base+i;
    if (e < E) atomicAdd(&h[ei[E+e]>>9], 1);
  }
  __syncthreads();
  int c = h[t];
  cur[t] = c ? atomicAdd(&bcur[t], c) : 0;
  __syncthreads();
  for (int i=t; i<EPB; i+=256){
    int e = base+i;
    if (e < E){
      int s = ei[e], d = ei[E+e], ty = et[e];
      int p = atomicAdd(&cur[d>>9], 1);
      bk[p] = ((uint)s<<10) | (uint)(((d&511)<<1) | ty);
    }
  }
}

// per-bucket fine sort: deg, pos (segment START), ssrc within 64KB window
__global__ __launch_bounds__(256) void k_csr(const uint* __restrict__ bk,
    const int* __restrict__ bbase, int* __restrict__ deg,
    int* __restrict__ pos, int* __restrict__ ssrc, int N){
  __shared__ int h[1024];
  __shared__ int cur[1024];
  __shared__ int ws[256];
  int b = blockIdx.x, t = threadIdx.x;
  int start = bbase[b], end = bbase[b+1];
  h[t]=0; h[256+t]=0; h[512+t]=0; h[768+t]=0;
  __syncthreads();
  for (int i=start+t; i<end; i+=256) atomicAdd(&h[bk[i]&1023], 1);
  __syncthreads();
  int c0=h[4*t], c1=h[4*t+1], c2=h[4*t+2], c3=h[4*t+3];
  int s = c0+c1+c2+c3;
  ws[t] = s; __syncthreads();
  for (int off=1; off<256; off<<=1){
    int tmp = (t>=off)? ws[t-off]:0;
    __syncthreads();
    ws[t] += tmp;
    __syncthreads();
  }
  int base0 = start + ws[t] - s;
  cur[4*t]   = base0;
  cur[4*t+1] = base0 + c0;
  cur[4*t+2] = base0 + c0 + c1;
  cur[4*t+3] = base0 + c0 + c1 + c2;
  int gk = b*1024 + 4*t;
  int nodeA = (b<<9) + 2*t, nodeB = nodeA + 1;
  if (nodeA < N){
    deg[gk]   = c0; deg[gk+1] = c1;
    pos[gk]   = base0; pos[gk+1] = base0 + c0;
  }
  if (nodeB < N){
    deg[gk+2] = c2; deg[gk+3] = c3;
    pos[gk+2] = base0 + c0 + c1; pos[gk+3] = base0 + c0 + c1 + c2;
  }
  __syncthreads();
  for (int i=start+t; i<end; i+=256){
    uint w = bk[i];
    int p = atomicAdd(&cur[w & 1023], 1);
    ssrc[p] = (int)(w >> 10);
  }
}

// ----------------------- gather (64-ch bf16 features) ---------------------
// Per-segment uniform loop. 16 lanes cover one 128B row (uint2 = 4ch/lane),
// 4 edge groups (eg). ssrc index via broadcast load (16 lanes same addr).
__device__ __forceinline__ float4 seg_sum64(const ushort* __restrict__ hp,
    const int* __restrict__ ssrc, int p, int d, int c4, int eg){
  float4 s = {0.f,0.f,0.f,0.f};
  int e = 0;
  for (; e+4 <= d; e += 4){
    int si = ssrc[p + e + eg];
    uint2 w = *(const uint2*)(hp + (size_t)si*64 + c4*4);
    s.x += __uint_as_float(w.x<<16);
    s.y += __uint_as_float(w.x & 0xffff0000u);
    s.z += __uint_as_float(w.y<<16);
    s.w += __uint_as_float(w.y & 0xffff0000u);
  }
  if (e < d){
    int idx = e + eg;
    uint2 w = {0u,0u};
    if (idx < d){
      int si = ssrc[p + idx];
      w = *(const uint2*)(hp + (size_t)si*64 + c4*4);
    }
    s.x += __uint_as_float(w.x<<16);
    s.y += __uint_as_float(w.x & 0xffff0000u);
    s.z += __uint_as_float(w.y<<16);
    s.w += __uint_as_float(w.y & 0xffff0000u);
  }
  s.x += __shfl_xor(s.x,16); s.x += __shfl_xor(s.x,32);
  s.y += __shfl_xor(s.y,16); s.y += __shfl_xor(s.y,32);
  s.z += __shfl_xor(s.z,16); s.z += __shfl_xor(s.z,32);
  s.w += __shfl_xor(s.w,16); s.w += __shfl_xor(s.w,32);
  return s;
}

__global__ __launch_bounds__(256) void k_gather64(
    const ushort* __restrict__ hp, const int* __restrict__ deg,
    const int* __restrict__ pos, const int* __restrict__ ssrc,
    ushort* __restrict__ sn, int N)
{
  int lane = threadIdx.x & 63;
  int wid  = (blockIdx.x*256 + threadIdx.x) >> 6;
  int c4 = lane & 15, eg = lane >> 4;
  int nA = wid*2, nB = nA+1;
  if (nA >= N) return;
  int d0A = deg[2*nA], d1A = deg[2*nA+1];
  int p0A = pos[2*nA], p1A = pos[2*nA+1];
  int d0B = 0, d1B = 0, p0B = 0, p1B = 0;
  if (nB < N){ d0B = deg[2*nB]; d1B = deg[2*nB+1]; p0B = pos[2*nB]; p1B = pos[2*nB+1]; }

  float4 s0A = seg_sum64(hp, ssrc, p0A, d0A, c4, eg);
  float4 s1A = seg_sum64(hp, ssrc, p1A, d1A, c4, eg);
  float4 s0B = seg_sum64(hp, ssrc, p0B, d0B, c4, eg);
  float4 s1B = seg_sum64(hp, ssrc, p1B, d1B, c4, eg);

  float i0A = 1.f/(float)(d0A>1?d0A:1), i1A = 1.f/(float)(d1A>1?d1A:1);
  float i0B = 1.f/(float)(d0B>1?d0B:1), i1B = 1.f/(float)(d1B>1?d1B:1);
  s0A.x*=i0A; s0A.y*=i0A; s0A.z*=i0A; s0A.w*=i0A;
  s1A.x*=i1A; s1A.y*=i1A; s1A.z*=i1A; s1A.w*=i1A;
  s0B.x*=i0B; s0B.y*=i0B; s0B.z*=i0B; s0B.w*=i0B;
  s1B.x*=i1B; s1B.y*=i1B; s1B.z*=i1B; s1B.w*=i1B;
  // lanes 0-15: (A,rel0) 16-31: (A,rel1) 32-47: (B,rel0) 48-63: (B,rel1)
  float4 v = (lane < 32) ? ((lane < 16) ? s0A : s1A)
                         : ((lane < 48) ? s0B : s1B);
  int n   = (lane < 32) ? nA : nB;
  int rel = (lane >> 4) & 1;
  if (n < N){
    uint2 pkt; pkt.x = bfpack2(v.x, v.y); pkt.y = bfpack2(v.z, v.w);
    *(uint2*)(sn + (size_t)n*128 + rel*64 + c4*4) = pkt;
  }
}

// ------------------------ gather (8-ch f32 input x) -----------------------
__device__ __forceinline__ float seg_sum8(const float* __restrict__ xp,
    const int* __restrict__ ssrc, int p, int d, int c, int eg){
  float s = 0.f;
  int e = 0;
  for (; e+8 <= d; e += 8){
    int si = ssrc[p + e + eg];
    s += xp[(size_t)si*8 + c];
  }
  if (e < d){
    int idx = e + eg;
    float v = 0.f;
    if (idx < d){
      int si = ssrc[p + idx];
      v = xp[(size_t)si*8 + c];
    }
    s += v;
  }
  s += __shfl_xor(s, 8); s += __shfl_xor(s, 16); s += __shfl_xor(s, 32);
  return s;
}

__global__ __launch_bounds__(256) void k_gather8(
    const float* __restrict__ xp, const int* __restrict__ deg,
    const int* __restrict__ pos, const int* __restrict__ ssrc,
    float* __restrict__ sn1, int N)
{
  int lane = threadIdx.x & 63;
  int wid  = (blockIdx.x*256 + threadIdx.x) >> 6;
  int c = lane & 7, eg = lane >> 3;
  int nA = wid*2, nB = nA+1;
  if (nA >= N) return;
  int d0A = deg[2*nA], d1A = deg[2*nA+1];
  int p0A = pos[2*nA], p1A = pos[2*nA+1];
  int d0B = 0, d1B = 0, p0B = 0, p1B = 0;
  if (nB < N){ d0B = deg[2*nB]; d1B = deg[2*nB+1]; p0B = pos[2*nB]; p1B = pos[2*nB+1]; }

  float s0A = seg_sum8(xp, ssrc, p0A, d0A, c, eg);
  float s1A = seg_sum8(xp, ssrc, p1A, d1A, c, eg);
  float s0B = seg_sum8(xp, ssrc, p0B, d0B, c, eg);
  float s1B = seg_sum8(xp, ssrc, p1B, d1B, c, eg);

  s0A *= 1.f/(float)(d0A>1?d0A:1);  s1A *= 1.f/(float)(d1A>1?d1A:1);
  s0B *= 1.f/(float)(d0B>1?d0B:1);  s1B *= 1.f/(float)(d1B>1?d1B:1);
  // lanes 0-7:(A,r0) 8-15:(A,r1) 16-23:(B,r0) 24-31:(B,r1)
  if (lane < 32){
    float v = (lane < 16) ? ((lane & 8) ? s1A : s0A)
                          : ((lane & 8) ? s1B : s0B);
    int n = (lane < 16) ? nA : nB;
    if (n < N) sn1[(size_t)n*16 + (lane & 15)] = v;
  }
}

// ----------------------- GEMM layers 2/3 (K=192) --------------------------
#define AST 196
template<int RELU, int OUTBF>
__global__ __launch_bounds__(256) void k_mm192(
    const ushort* __restrict__ sn,   // [N,128] bf16 (rel0|rel1 means)
    const ushort* __restrict__ hp,   // [N,64]  bf16 self
    const float* __restrict__ Wl,    // [128,64]
    const float* __restrict__ rootp, // [64,64]
    const float* __restrict__ bias, void* __restrict__ hout_, int N)
{
  __shared__ float A[64*AST];
  int t = threadIdx.x;
  int nb = blockIdx.x*64;
  #pragma unroll
  for (int k=0;k<4;++k){
    int q = k*256 + t;
    int nl = q>>4, off = q&15;
    int n = nb + nl;
    uint4 w = {0,0,0,0};
    if (n < N) w = *(const uint4*)(sn + (size_t)n*128 + off*8);
    float2 a = bf2cvt(w.x), b = bf2cvt(w.y), c = bf2cvt(w.z), d = bf2cvt(w.w);
    float* dst = &A[nl*AST + off*8];
    float4 lo = {a.x,a.y,b.x,b.y}, hi = {c.x,c.y,d.x,d.y};
    *(float4*)dst = lo; *(float4*)(dst+4) = hi;
  }
  #pragma unroll
  for (int k=0;k<2;++k){
    int q = k*256 + t;
    int nl = q>>3, off = q&7;
    int n = nb + nl;
    uint4 w = {0,0,0,0};
    if (n < N) w = *(const uint4*)(hp + (size_t)n*64 + off*8);
    float2 a = bf2cvt(w.x), b = bf2cvt(w.y), c = bf2cvt(w.z), d = bf2cvt(w.w);
    float* dst = &A[nl*AST + 128 + off*8];
    float4 lo = {a.x,a.y,b.x,b.y}, hi = {c.x,c.y,d.x,d.y};
    *(float4*)dst = lo; *(float4*)(dst+4) = hi;
  }
  __syncthreads();
  int o0 = (t&15)*4, r0 = (t>>4)*4;
  float4 b4 = *(const float4*)(bias+o0);
  float4 a0=b4,a1=b4,a2=b4,a3=b4;
  const float* Ab = &A[r0*AST];
  #pragma unroll 4
  for (int i=0;i<128;++i){
    float4 w = *(const float4*)(Wl + i*64 + o0);
    fma4(a0, Ab[i],       w); fma4(a1, Ab[AST+i],   w);
    fma4(a2, Ab[2*AST+i], w); fma4(a3, Ab[3*AST+i], w);
  }
  #pragma unroll 4
  for (int i=0;i<64;++i){
    float4 w = *(const float4*)(rootp + i*64 + o0);
    fma4(a0, Ab[128+i],       w); fma4(a1, Ab[AST+128+i],   w);
    fma4(a2, Ab[2*AST+128+i], w); fma4(a3, Ab[3*AST+128+i], w);
  }
  float4 accs[4] = {a0,a1,a2,a3};
  #pragma unroll
  for (int q=0;q<4;++q){
    int n = nb + r0 + q;
    if (n < N){
      float4 r = accs[q];
      if (RELU){ r.x=fmaxf(r.x,0.f); r.y=fmaxf(r.y,0.f); r.z=fmaxf(r.z,0.f); r.w=fmaxf(r.w,0.f); }
      if (OUTBF){
        uint2 p; p.x = bfpack2(r.x,r.y); p.y = bfpack2(r.z,r.w);
        *(uint2*)((ushort*)hout_ + (size_t)n*64 + o0) = p;
      } else {
        *(float4*)((float*)hout_ + (size_t)n*64 + o0) = r;
      }
    }
  }
}

// -------------------------- GEMM layer 1 (K=24) ---------------------------
__global__ __launch_bounds__(256) void k_mm24(
    const float* __restrict__ sn1,   // [N,16] f32
    const float* __restrict__ xp,    // [N,8] f32 self
    const float* __restrict__ Wl,    // [16,64]
    const float* __restrict__ rootp, // [8,64]
    const float* __restrict__ bias, ushort* __restrict__ hout, int N)
{
  __shared__ float A[64*25];
  int t = threadIdx.x;
  int nb = blockIdx.x*64;
  #pragma unroll
  for (int k=0;k<4;++k){
    int q = k*256 + t;
    int nl = q>>4, c = q&15;
    int n = nb + nl;
    A[nl*25 + c] = (n < N) ? sn1[(size_t)n*16 + c] : 0.f;
  }
  #pragma unroll
  for (int k=0;k<2;++k){
    int q = k*256 + t;
    int nl = q>>3, c = q&7;
    int n = nb + nl;
    A[nl*25 + 16 + c] = (n < N) ? xp[(size_t)n*8 + c] : 0.f;
  }
  __syncthreads();
  int o0=(t&15)*4, r0=(t>>4)*4;
  float4 b4 = *(const float4*)(bias+o0);
  float4 a0=b4,a1=b4,a2=b4,a3=b4;
  const float* Ab=&A[r0*25];
  #pragma unroll
  for (int i=0;i<16;++i){
    float4 w=*(const float4*)(Wl+i*64+o0);
    fma4(a0,Ab[i],w); fma4(a1,Ab[25+i],w); fma4(a2,Ab[50+i],w); fma4(a3,Ab[75+i],w);
  }
  #pragma unroll
  for (int i=0;i<8;++i){
    float4 w=*(const float4*)(rootp+i*64+o0);
    fma4(a0,Ab[16+i],w); fma4(a1,Ab[41+i],w); fma4(a2,Ab[66+i],w); fma4(a3,Ab[91+i],w);
  }
  float4 accs[4]={a0,a1,a2,a3};
  #pragma unroll
  for (int q=0;q<4;++q){
    int n = nb + r0 + q;
    if (n < N){
      float4 r = accs[q];
      r.x=fmaxf(r.x,0.f); r.y=fmaxf(r.y,0.f); r.z=fmaxf(r.z,0.f); r.w=fmaxf(r.w,0.f);
      uint2 p; p.x = bfpack2(r.x,r.y); p.y = bfpack2(r.z,r.w);
      *(uint2*)(hout + (size_t)n*64 + o0) = p;
    }
  }
}

// ------------------------------- pool + MLP -------------------------------

__device__ __forceinline__ int lowerb(const int* __restrict__ b, int n, int key){
  int lo=0, hi=n;
  while (lo<hi){ int mid=(lo+hi)>>1; if (b[mid]<key) lo=mid+1; else hi=mid; }
  return lo;
}

__global__ __launch_bounds__(256) void k_pool(const float* __restrict__ h,
    const int* __restrict__ batch, float* __restrict__ gp, int N){
  __shared__ float red[256];
  int g=blockIdx.x, t=threadIdx.x;
  int start=lowerb(batch,N,g), end=lowerb(batch,N,g+1);
  int c=t&63, p=t>>6;
  float s=0.f;
  for (int n=start+p; n<end; n+=4) s += h[(size_t)n*64+c];
  red[t]=s; __syncthreads();
  if (t<64) gp[g*64+c] = red[c]+red[64+c]+red[128+c]+red[192+c];
}

// one wave per graph: lane l -> hidden j=l&31, half=l>>5
__global__ __launch_bounds__(256) void k_clf(const float* __restrict__ gp,
    const float* __restrict__ cW1, const float* __restrict__ cb1,
    const float* __restrict__ cW2, const float* __restrict__ cb2,
    float* __restrict__ out, int G){
  int lane = threadIdx.x & 63;
  int g = (blockIdx.x*256 + threadIdx.x) >> 6;
  if (g >= G) return;
  int j = lane & 31, half = lane >> 5;
  const float* gv = gp + (size_t)g*64 + half*32;
  const float* Wc = cW1 + half*32*32 + j;
  float s = 0.f;
  #pragma unroll 8
  for (int i=0;i<32;++i) s += gv[i] * Wc[i*32];
  s += __shfl_xor(s, 32);
  s = fmaxf(s + cb1[j], 0.f) * cW2[j];
  s += __shfl_xor(s, 1);  s += __shfl_xor(s, 2);
  s += __shfl_xor(s, 4);  s += __shfl_xor(s, 8);
  s += __shfl_xor(s, 16);
  if (lane == 0) out[g] = s + cb2[0];
}

extern "C" void kernel_launch(void* const* d_in, const int* in_sizes, int n_in,
                              void* d_out, int out_size, void* d_ws, size_t ws_size,
                              hipStream_t stream){
  const float* x     = (const float*)d_in[0];
  const int*   ei    = (const int*)d_in[1];
  const int*   et    = (const int*)d_in[2];
  const int*   batch = (const int*)d_in[3];
  const float* W1    = (const float*)d_in[4];
  const float* root1 = (const float*)d_in[5];
  const float* b1    = (const float*)d_in[6];
  const float* W2    = (const float*)d_in[7];
  const float* root2 = (const float*)d_in[8];
  const float* b2    = (const float*)d_in[9];
  const float* W3    = (const float*)d_in[10];
  const float* root3 = (const float*)d_in[11];
  const float* b3    = (const float*)d_in[12];
  const float* cW1   = (const float*)d_in[13];
  const float* cb1   = (const float*)d_in[14];
  const float* cW2   = (const float*)d_in[15];
  const float* cb2   = (const float*)d_in[16];
  float* out = (float*)d_out;
  (void)n_in; (void)ws_size;

  int N = in_sizes[0]/8;      // 100000
  int E = in_sizes[2];        // 3200000
  int G = out_size;           // 256
  int M = 2*N;

  char* w = (char*)d_ws;
  auto alloc=[&](size_t bytes)->char*{ char* p=w; w += (bytes+255)&~(size_t)255; return p; };
  int*    bhist = (int*)alloc(256*4);
  int*    bbase = (int*)alloc(257*4);
  int*    bcur  = (int*)alloc(256*4);
  int*    ssrc  = (int*)alloc((size_t)E*4);
  int*    deg   = (int*)alloc((size_t)M*4);
  int*    pos   = (int*)alloc((size_t)M*4);
  ushort* h1    = (ushort*)alloc((size_t)N*64*2);
  ushort* snU   = (ushort*)alloc((size_t)N*128*2);
  ushort* h2    = (ushort*)alloc((size_t)N*64*2);  // bk aliases this
  float*  gp    = (float*)alloc((size_t)G*64*4);
  uint*   bk    = (uint*)h2;                       // dead before h2 is written
  float*  sn1   = (float*)snU;                     // [N,16] f32, dead after k_mm24
  float*  hf    = (float*)ssrc;                    // [N,64] f32 spans ssrc+deg+pos+h1, all dead at layer-3 GEMM

  hipMemsetAsync(bhist, 0, 256*4, stream);
  int nbE = (E + EPB - 1)/EPB;
  k_count<<<nbE,256,0,stream>>>(ei,bhist,E);
  k_bscan<<<1,256,0,stream>>>(bhist,bbase,bcur);
  k_part <<<nbE,256,0,stream>>>(ei,et,bcur,bk,E);
  k_csr  <<<256,256,0,stream>>>(bk,bbase,deg,pos,ssrc,N);

  int gb = (((N+1)/2) + 3) / 4;     // waves = ceil(N/2), 4 waves/block
  int nbk = (N+63)/64;
  // layer 1
  k_gather8 <<<gb,256,0,stream>>>(x,deg,pos,ssrc,sn1,N);
  k_mm24    <<<nbk,256,0,stream>>>(sn1,x,W1,root1,b1,h1,N);
  // layer 2
  k_gather64<<<gb,256,0,stream>>>(h1,deg,pos,ssrc,snU,N);
  k_mm192<1,1><<<nbk,256,0,stream>>>(snU,h1,W2,root2,b2,h2,N);
  // layer 3
  k_gather64<<<gb,256,0,stream>>>(h2,deg,pos,ssrc,snU,N);
  k_mm192<0,0><<<nbk,256,0,stream>>>(snU,h2,W3,root3,b3,hf,N);
  // pool + head
  k_pool<<<G,256,0,stream>>>(hf,batch,gp,N);
  k_clf<<<(G*64+255)/256,256,0,stream>>>(gp,cW1,cb1,cW2,cb2,out,G);
}

// Round 7
// 549.111 us; speedup vs baseline: 1.0990x; 1.0990x over previous
//
#include <hip/hip_runtime.h>

// ---------------------------------------------------------------------------
// RGCN restructured: aggregate x[src] FIRST (per relation), then one GEMM
//   A = [Sn_rel0 | Sn_rel1 | x_self],  Wcat = [W0; W1; root]
// R4: CSR build via two-level counting sort (cache-resident random writes).
// R5: k_clf one wave per graph.
// R7: gather = staged-shfl indices (R5: keeps feature loads off a dependent
//     index-load chain — R6's broadcast-load regressed 63->100us, VALUBusy
//     96->37%) + per-segment uniform loops (R6: kills accsel/guards) +
//     2-deep unroll (2 loads in flight).
// ---------------------------------------------------------------------------

typedef unsigned int uint;
typedef unsigned short ushort;

#define EPB 8192   // edges per block in count/partition kernels

__device__ __forceinline__ void fma4(float4& a, float s, const float4& w){
  a.x += s*w.x; a.y += s*w.y; a.z += s*w.z; a.w += s*w.w;
}
__device__ __forceinline__ uint bf1(float f){          // f32 -> bf16 (RNE)
  uint u = __float_as_uint(f);
  return (u + 0x7fffu + ((u>>16)&1u)) >> 16;
}
__device__ __forceinline__ uint bfpack2(float lo, float hi){
  return bf1(lo) | (bf1(hi)<<16);
}
__device__ __forceinline__ float2 bf2cvt(uint w){
  float2 r; r.x = __uint_as_float(w<<16); r.y = __uint_as_float(w & 0xffff0000u);
  return r;
}
__device__ __forceinline__ void bfacc(uint2 w, float4& s){
  s.x += __uint_as_float(w.x<<16);
  s.y += __uint_as_float(w.x & 0xffff0000u);
  s.z += __uint_as_float(w.y<<16);
  s.w += __uint_as_float(w.y & 0xffff0000u);
}

// --------------------- CSR build: two-level counting sort ------------------

__global__ __launch_bounds__(256) void k_count(const int* __restrict__ ei,
    int* __restrict__ bhist, int E){
  __shared__ int h[256];
  int t = threadIdx.x;
  h[t] = 0; __syncthreads();
  int base = blockIdx.x*EPB;
  for (int i=t; i<EPB; i+=256){
    int e = base+i;
    if (e < E) atomicAdd(&h[ei[E+e]>>9], 1);
  }
  __syncthreads();
  if (h[t]) atomicAdd(&bhist[t], h[t]);
}

__global__ __launch_bounds__(256) void k_bscan(const int* __restrict__ bhist,
    int* __restrict__ bbase, int* __restrict__ bcur){
  __shared__ int lds[256];
  int t = threadIdx.x;
  int v = bhist[t];
  lds[t] = v; __syncthreads();
  for (int off=1; off<256; off<<=1){
    int tmp = (t>=off)? lds[t-off]:0;
    __syncthreads();
    lds[t] += tmp;
    __syncthreads();
  }
  int excl = lds[t]-v;
  bbase[t] = excl; bcur[t] = excl;
  if (t==255) bbase[256] = excl+v;
}

// partition edges into bucket regions as packed (src<<10)|((dst&511)<<1|ty)
__global__ __launch_bounds__(256) void k_part(const int* __restrict__ ei,
    const int* __restrict__ et, int* __restrict__ bcur,
    uint* __restrict__ bk, int E){
  __shared__ int h[256];
  __shared__ int cur[256];
  int t = threadIdx.x;
  h[t] = 0; __syncthreads();
  int base = blockIdx.x*EPB;
  for (int i=t; i<EPB; i+=256){
    int e = base+i;
    if (e < E) atomicAdd(&h[ei[E+e]>>9], 1);
  }
  __syncthreads();
  int c = h[t];
  cur[t] = c ? atomicAdd(&bcur[t], c) : 0;
  __syncthreads();
  for (int i=t; i<EPB; i+=256){
    int e = base+i;
    if (e < E){
      int s = ei[e], d = ei[E+e], ty = et[e];
      int p = atomicAdd(&cur[d>>9], 1);
      bk[p] = ((uint)s<<10) | (uint)(((d&511)<<1) | ty);
    }
  }
}

// per-bucket fine sort: deg, pos (segment START), ssrc within 64KB window
__global__ __launch_bounds__(256) void k_csr(const uint* __restrict__ bk,
    const int* __restrict__ bbase, int* __restrict__ deg,
    int* __restrict__ pos, int* __restrict__ ssrc, int N){
  __shared__ int h[1024];
  __shared__ int cur[1024];
  __shared__ int ws[256];
  int b = blockIdx.x, t = threadIdx.x;
  int start = bbase[b], end = bbase[b+1];
  h[t]=0; h[256+t]=0; h[512+t]=0; h[768+t]=0;
  __syncthreads();
  for (int i=start+t; i<end; i+=256) atomicAdd(&h[bk[i]&1023], 1);
  __syncthreads();
  int c0=h[4*t], c1=h[4*t+1], c2=h[4*t+2], c3=h[4*t+3];
  int s = c0+c1+c2+c3;
  ws[t] = s; __syncthreads();
  for (int off=1; off<256; off<<=1){
    int tmp = (t>=off)? ws[t-off]:0;
    __syncthreads();
    ws[t] += tmp;
    __syncthreads();
  }
  int base0 = start + ws[t] - s;
  cur[4*t]   = base0;
  cur[4*t+1] = base0 + c0;
  cur[4*t+2] = base0 + c0 + c1;
  cur[4*t+3] = base0 + c0 + c1 + c2;
  int gk = b*1024 + 4*t;
  int nodeA = (b<<9) + 2*t, nodeB = nodeA + 1;
  if (nodeA < N){
    deg[gk]   = c0; deg[gk+1] = c1;
    pos[gk]   = base0; pos[gk+1] = base0 + c0;
  }
  if (nodeB < N){
    deg[gk+2] = c2; deg[gk+3] = c3;
    pos[gk+2] = base0 + c0 + c1; pos[gk+3] = base0 + c0 + c1 + c2;
  }
  __syncthreads();
  for (int i=start+t; i<end; i+=256){
    uint w = bk[i];
    int p = atomicAdd(&cur[w & 1023], 1);
    ssrc[p] = (int)(w >> 10);
  }
}

// ----------------------- gather (64-ch bf16 features) ---------------------
// Per-segment uniform loop, indices STAGED in a register (coalesced load)
// and broadcast via shfl -- feature loads never wait on an index load.
// 16 lanes per 128B row (uint2 = 4 ch/lane), 4 edge groups, 2-deep unroll.
__device__ __forceinline__ float4 seg_sum64(const ushort* __restrict__ hp,
    const int* __restrict__ ssrc, int p, int d, int lane, int c4, int eg){
  float4 s = {0.f,0.f,0.f,0.f};
  int j = 0;
  while (j < d){
    int take = d - j; if (take > 64) take = 64;
    int sv = (lane < take) ? ssrc[p + j + lane] : 0;
    int e = 0;
    for (; e+8 <= take; e += 8){
      int si0 = __shfl(sv, e+eg);
      int si1 = __shfl(sv, e+4+eg);
      uint2 w0 = *(const uint2*)(hp + (size_t)si0*64 + c4*4);
      uint2 w1 = *(const uint2*)(hp + (size_t)si1*64 + c4*4);
      bfacc(w0, s); bfacc(w1, s);
    }
    for (; e < take; e += 4){
      int idx = e + eg;
      int si = __shfl(sv, idx < take ? idx : 0);
      uint2 w = {0u,0u};
      if (idx < take) w = *(const uint2*)(hp + (size_t)si*64 + c4*4);
      bfacc(w, s);
    }
    j += take;
  }
  s.x += __shfl_xor(s.x,16); s.x += __shfl_xor(s.x,32);
  s.y += __shfl_xor(s.y,16); s.y += __shfl_xor(s.y,32);
  s.z += __shfl_xor(s.z,16); s.z += __shfl_xor(s.z,32);
  s.w += __shfl_xor(s.w,16); s.w += __shfl_xor(s.w,32);
  return s;
}

__global__ __launch_bounds__(256) void k_gather64(
    const ushort* __restrict__ hp, const int* __restrict__ deg,
    const int* __restrict__ pos, const int* __restrict__ ssrc,
    ushort* __restrict__ sn, int N)
{
  int lane = threadIdx.x & 63;
  int wid  = (blockIdx.x*256 + threadIdx.x) >> 6;
  int c4 = lane & 15, eg = lane >> 4;
  int nA = wid*2, nB = nA+1;
  if (nA >= N) return;
  int d0A = deg[2*nA], d1A = deg[2*nA+1];
  int p0A = pos[2*nA], p1A = pos[2*nA+1];
  int d0B = 0, d1B = 0, p0B = 0, p1B = 0;
  if (nB < N){ d0B = deg[2*nB]; d1B = deg[2*nB+1]; p0B = pos[2*nB]; p1B = pos[2*nB+1]; }

  float4 s0A = seg_sum64(hp, ssrc, p0A, d0A, lane, c4, eg);
  float4 s1A = seg_sum64(hp, ssrc, p1A, d1A, lane, c4, eg);
  float4 s0B = seg_sum64(hp, ssrc, p0B, d0B, lane, c4, eg);
  float4 s1B = seg_sum64(hp, ssrc, p1B, d1B, lane, c4, eg);

  float i0A = 1.f/(float)(d0A>1?d0A:1), i1A = 1.f/(float)(d1A>1?d1A:1);
  float i0B = 1.f/(float)(d0B>1?d0B:1), i1B = 1.f/(float)(d1B>1?d1B:1);
  s0A.x*=i0A; s0A.y*=i0A; s0A.z*=i0A; s0A.w*=i0A;
  s1A.x*=i1A; s1A.y*=i1A; s1A.z*=i1A; s1A.w*=i1A;
  s0B.x*=i0B; s0B.y*=i0B; s0B.z*=i0B; s0B.w*=i0B;
  s1B.x*=i1B; s1B.y*=i1B; s1B.z*=i1B; s1B.w*=i1B;
  // lanes 0-15: (A,rel0) 16-31: (A,rel1) 32-47: (B,rel0) 48-63: (B,rel1)
  float4 v = (lane < 32) ? ((lane < 16) ? s0A : s1A)
                         : ((lane < 48) ? s0B : s1B);
  int n   = (lane < 32) ? nA : nB;
  int rel = (lane >> 4) & 1;
  if (n < N){
    uint2 pkt; pkt.x = bfpack2(v.x, v.y); pkt.y = bfpack2(v.z, v.w);
    *(uint2*)(sn + (size_t)n*128 + rel*64 + c4*4) = pkt;
  }
}

// ------------------------ gather (8-ch f32 input x) -----------------------
__device__ __forceinline__ float seg_sum8(const float* __restrict__ xp,
    const int* __restrict__ ssrc, int p, int d, int lane, int c, int eg){
  float s = 0.f;
  int j = 0;
  while (j < d){
    int take = d - j; if (take > 64) take = 64;
    int sv = (lane < take) ? ssrc[p + j + lane] : 0;
    int e = 0;
    for (; e+16 <= take; e += 16){
      int si0 = __shfl(sv, e+eg);
      int si1 = __shfl(sv, e+8+eg);
      s += xp[(size_t)si0*8 + c];
      s += xp[(size_t)si1*8 + c];
    }
    for (; e < take; e += 8){
      int idx = e + eg;
      int si = __shfl(sv, idx < take ? idx : 0);
      float v = 0.f;
      if (idx < take) v = xp[(size_t)si*8 + c];
      s += v;
    }
    j += take;
  }
  s += __shfl_xor(s, 8); s += __shfl_xor(s, 16); s += __shfl_xor(s, 32);
  return s;
}

__global__ __launch_bounds__(256) void k_gather8(
    const float* __restrict__ xp, const int* __restrict__ deg,
    const int* __restrict__ pos, const int* __restrict__ ssrc,
    float* __restrict__ sn1, int N)
{
  int lane = threadIdx.x & 63;
  int wid  = (blockIdx.x*256 + threadIdx.x) >> 6;
  int c = lane & 7, eg = lane >> 3;
  int nA = wid*2, nB = nA+1;
  if (nA >= N) return;
  int d0A = deg[2*nA], d1A = deg[2*nA+1];
  int p0A = pos[2*nA], p1A = pos[2*nA+1];
  int d0B = 0, d1B = 0, p0B = 0, p1B = 0;
  if (nB < N){ d0B = deg[2*nB]; d1B = deg[2*nB+1]; p0B = pos[2*nB]; p1B = pos[2*nB+1]; }

  float s0A = seg_sum8(xp, ssrc, p0A, d0A, lane, c, eg);
  float s1A = seg_sum8(xp, ssrc, p1A, d1A, lane, c, eg);
  float s0B = seg_sum8(xp, ssrc, p0B, d0B, lane, c, eg);
  float s1B = seg_sum8(xp, ssrc, p1B, d1B, lane, c, eg);

  s0A *= 1.f/(float)(d0A>1?d0A:1);  s1A *= 1.f/(float)(d1A>1?d1A:1);
  s0B *= 1.f/(float)(d0B>1?d0B:1);  s1B *= 1.f/(float)(d1B>1?d1B:1);
  // lanes 0-7:(A,r0) 8-15:(A,r1) 16-23:(B,r0) 24-31:(B,r1)
  if (lane < 32){
    float v = (lane < 16) ? ((lane & 8) ? s1A : s0A)
                          : ((lane & 8) ? s1B : s0B);
    int n = (lane < 16) ? nA : nB;
    if (n < N) sn1[(size_t)n*16 + (lane & 15)] = v;
  }
}

// ----------------------- GEMM layers 2/3 (K=192) --------------------------
#define AST 196
template<int RELU, int OUTBF>
__global__ __launch_bounds__(256) void k_mm192(
    const ushort* __restrict__ sn,   // [N,128] bf16 (rel0|rel1 means)
    const ushort* __restrict__ hp,   // [N,64]  bf16 self
    const float* __restrict__ Wl,    // [128,64]
    const float* __restrict__ rootp, // [64,64]
    const float* __restrict__ bias, void* __restrict__ hout_, int N)
{
  __shared__ float A[64*AST];
  int t = threadIdx.x;
  int nb = blockIdx.x*64;
  #pragma unroll
  for (int k=0;k<4;++k){
    int q = k*256 + t;
    int nl = q>>4, off = q&15;
    int n = nb + nl;
    uint4 w = {0,0,0,0};
    if (n < N) w = *(const uint4*)(sn + (size_t)n*128 + off*8);
    float2 a = bf2cvt(w.x), b = bf2cvt(w.y), c = bf2cvt(w.z), d = bf2cvt(w.w);
    float* dst = &A[nl*AST + off*8];
    float4 lo = {a.x,a.y,b.x,b.y}, hi = {c.x,c.y,d.x,d.y};
    *(float4*)dst = lo; *(float4*)(dst+4) = hi;
  }
  #pragma unroll
  for (int k=0;k<2;++k){
    int q = k*256 + t;
    int nl = q>>3, off = q&7;
    int n = nb + nl;
    uint4 w = {0,0,0,0};
    if (n < N) w = *(const uint4*)(hp + (size_t)n*64 + off*8);
    float2 a = bf2cvt(w.x), b = bf2cvt(w.y), c = bf2cvt(w.z), d = bf2cvt(w.w);
    float* dst = &A[nl*AST + 128 + off*8];
    float4 lo = {a.x,a.y,b.x,b.y}, hi = {c.x,c.y,d.x,d.y};
    *(float4*)dst = lo; *(float4*)(dst+4) = hi;
  }
  __syncthreads();
  int o0 = (t&15)*4, r0 = (t>>4)*4;
  float4 b4 = *(const float4*)(bias+o0);
  float4 a0=b4,a1=b4,a2=b4,a3=b4;
  const float* Ab = &A[r0*AST];
  #pragma unroll 4
  for (int i=0;i<128;++i){
    float4 w = *(const float4*)(Wl + i*64 + o0);
    fma4(a0, Ab[i],       w); fma4(a1, Ab[AST+i],   w);
    fma4(a2, Ab[2*AST+i], w); fma4(a3, Ab[3*AST+i], w);
  }
  #pragma unroll 4
  for (int i=0;i<64;++i){
    float4 w = *(const float4*)(rootp + i*64 + o0);
    fma4(a0, Ab[128+i],       w); fma4(a1, Ab[AST+128+i],   w);
    fma4(a2, Ab[2*AST+128+i], w); fma4(a3, Ab[3*AST+128+i], w);
  }
  float4 accs[4] = {a0,a1,a2,a3};
  #pragma unroll
  for (int q=0;q<4;++q){
    int n = nb + r0 + q;
    if (n < N){
      float4 r = accs[q];
      if (RELU){ r.x=fmaxf(r.x,0.f); r.y=fmaxf(r.y,0.f); r.z=fmaxf(r.z,0.f); r.w=fmaxf(r.w,0.f); }
      if (OUTBF){
        uint2 p; p.x = bfpack2(r.x,r.y); p.y = bfpack2(r.z,r.w);
        *(uint2*)((ushort*)hout_ + (size_t)n*64 + o0) = p;
      } else {
        *(float4*)((float*)hout_ + (size_t)n*64 + o0) = r;
      }
    }
  }
}

// -------------------------- GEMM layer 1 (K=24) ---------------------------
__global__ __launch_bounds__(256) void k_mm24(
    const float* __restrict__ sn1,   // [N,16] f32
    const float* __restrict__ xp,    // [N,8] f32 self
    const float* __restrict__ Wl,    // [16,64]
    const float* __restrict__ rootp, // [8,64]
    const float* __restrict__ bias, ushort* __restrict__ hout, int N)
{
  __shared__ float A[64*25];
  int t = threadIdx.x;
  int nb = blockIdx.x*64;
  #pragma unroll
  for (int k=0;k<4;++k){
    int q = k*256 + t;
    int nl = q>>4, c = q&15;
    int n = nb + nl;
    A[nl*25 + c] = (n < N) ? sn1[(size_t)n*16 + c] : 0.f;
  }
  #pragma unroll
  for (int k=0;k<2;++k){
    int q = k*256 + t;
    int nl = q>>3, c = q&7;
    int n = nb + nl;
    A[nl*25 + 16 + c] = (n < N) ? xp[(size_t)n*8 + c] : 0.f;
  }
  __syncthreads();
  int o0=(t&15)*4, r0=(t>>4)*4;
  float4 b4 = *(const float4*)(bias+o0);
  float4 a0=b4,a1=b4,a2=b4,a3=b4;
  const float* Ab=&A[r0*25];
  #pragma unroll
  for (int i=0;i<16;++i){
    float4 w=*(const float4*)(Wl+i*64+o0);
    fma4(a0,Ab[i],w); fma4(a1,Ab[25+i],w); fma4(a2,Ab[50+i],w); fma4(a3,Ab[75+i],w);
  }
  #pragma unroll
  for (int i=0;i<8;++i){
    float4 w=*(const float4*)(rootp+i*64+o0);
    fma4(a0,Ab[16+i],w); fma4(a1,Ab[41+i],w); fma4(a2,Ab[66+i],w); fma4(a3,Ab[91+i],w);
  }
  float4 accs[4]={a0,a1,a2,a3};
  #pragma unroll
  for (int q=0;q<4;++q){
    int n = nb + r0 + q;
    if (n < N){
      float4 r = accs[q];
      r.x=fmaxf(r.x,0.f); r.y=fmaxf(r.y,0.f); r.z=fmaxf(r.z,0.f); r.w=fmaxf(r.w,0.f);
      uint2 p; p.x = bfpack2(r.x,r.y); p.y = bfpack2(r.z,r.w);
      *(uint2*)(hout + (size_t)n*64 + o0) = p;
    }
  }
}

// ------------------------------- pool + MLP -------------------------------

__device__ __forceinline__ int lowerb(const int* __restrict__ b, int n, int key){
  int lo=0, hi=n;
  while (lo<hi){ int mid=(lo+hi)>>1; if (b[mid]<key) lo=mid+1; else hi=mid; }
  return lo;
}

__global__ __launch_bounds__(256) void k_pool(const float* __restrict__ h,
    const int* __restrict__ batch, float* __restrict__ gp, int N){
  __shared__ float red[256];
  int g=blockIdx.x, t=threadIdx.x;
  int start=lowerb(batch,N,g), end=lowerb(batch,N,g+1);
  int c=t&63, p=t>>6;
  float s=0.f;
  for (int n=start+p; n<end; n+=4) s += h[(size_t)n*64+c];
  red[t]=s; __syncthreads();
  if (t<64) gp[g*64+c] = red[c]+red[64+c]+red[128+c]+red[192+c];
}

// one wave per graph: lane l -> hidden j=l&31, half=l>>5
__global__ __launch_bounds__(256) void k_clf(const float* __restrict__ gp,
    const float* __restrict__ cW1, const float* __restrict__ cb1,
    const float* __restrict__ cW2, const float* __restrict__ cb2,
    float* __restrict__ out, int G){
  int lane = threadIdx.x & 63;
  int g = (blockIdx.x*256 + threadIdx.x) >> 6;
  if (g >= G) return;
  int j = lane & 31, half = lane >> 5;
  const float* gv = gp + (size_t)g*64 + half*32;
  const float* Wc = cW1 + half*32*32 + j;
  float s = 0.f;
  #pragma unroll 8
  for (int i=0;i<32;++i) s += gv[i] * Wc[i*32];
  s += __shfl_xor(s, 32);
  s = fmaxf(s + cb1[j], 0.f) * cW2[j];
  s += __shfl_xor(s, 1);  s += __shfl_xor(s, 2);
  s += __shfl_xor(s, 4);  s += __shfl_xor(s, 8);
  s += __shfl_xor(s, 16);
  if (lane == 0) out[g] = s + cb2[0];
}

extern "C" void kernel_launch(void* const* d_in, const int* in_sizes, int n_in,
                              void* d_out, int out_size, void* d_ws, size_t ws_size,
                              hipStream_t stream){
  const float* x     = (const float*)d_in[0];
  const int*   ei    = (const int*)d_in[1];
  const int*   et    = (const int*)d_in[2];
  const int*   batch = (const int*)d_in[3];
  const float* W1    = (const float*)d_in[4];
  const float* root1 = (const float*)d_in[5];
  const float* b1    = (const float*)d_in[6];
  const float* W2    = (const float*)d_in[7];
  const float* root2 = (const float*)d_in[8];
  const float* b2    = (const float*)d_in[9];
  const float* W3    = (const float*)d_in[10];
  const float* root3 = (const float*)d_in[11];
  const float* b3    = (const float*)d_in[12];
  const float* cW1   = (const float*)d_in[13];
  const float* cb1   = (const float*)d_in[14];
  const float* cW2   = (const float*)d_in[15];
  const float* cb2   = (const float*)d_in[16];
  float* out = (float*)d_out;
  (void)n_in; (void)ws_size;

  int N = in_sizes[0]/8;      // 100000
  int E = in_sizes[2];        // 3200000
  int G = out_size;           // 256
  int M = 2*N;

  char* w = (char*)d_ws;
  auto alloc=[&](size_t bytes)->char*{ char* p=w; w += (bytes+255)&~(size_t)255; return p; };
  int*    bhist = (int*)alloc(256*4);
  int*    bbase = (int*)alloc(257*4);
  int*    bcur  = (int*)alloc(256*4);
  int*    ssrc  = (int*)alloc((size_t)E*4);
  int*    deg   = (int*)alloc((size_t)M*4);
  int*    pos   = (int*)alloc((size_t)M*4);
  ushort* h1    = (ushort*)alloc((size_t)N*64*2);
  ushort* snU   = (ushort*)alloc((size_t)N*128*2);
  ushort* h2    = (ushort*)alloc((size_t)N*64*2);  // bk aliases this
  float*  gp    = (float*)alloc((size_t)G*64*4);
  uint*   bk    = (uint*)h2;                       // dead before h2 is written
  float*  sn1   = (float*)snU;                     // [N,16] f32, dead after k_mm24
  float*  hf    = (float*)ssrc;                    // [N,64] f32 spans ssrc+deg+pos+h1, all dead at layer-3 GEMM

  hipMemsetAsync(bhist, 0, 256*4, stream);
  int nbE = (E + EPB - 1)/EPB;
  k_count<<<nbE,256,0,stream>>>(ei,bhist,E);
  k_bscan<<<1,256,0,stream>>>(bhist,bbase,bcur);
  k_part <<<nbE,256,0,stream>>>(ei,et,bcur,bk,E);
  k_csr  <<<256,256,0,stream>>>(bk,bbase,deg,pos,ssrc,N);

  int gb = (((N+1)/2) + 3) / 4;     // waves = ceil(N/2), 4 waves/block
  int nbk = (N+63)/64;
  // layer 1
  k_gather8 <<<gb,256,0,stream>>>(x,deg,pos,ssrc,sn1,N);
  k_mm24    <<<nbk,256,0,stream>>>(sn1,x,W1,root1,b1,h1,N);
  // layer 2
  k_gather64<<<gb,256,0,stream>>>(h1,deg,pos,ssrc,snU,N);
  k_mm192<1,1><<<nbk,256,0,stream>>>(snU,h1,W2,root2,b2,h2,N);
  // layer 3
  k_gather64<<<gb,256,0,stream>>>(h2,deg,pos,ssrc,snU,N);
  k_mm192<0,0><<<nbk,256,0,stream>>>(snU,h2,W3,root3,b3,hf,N);
  // pool + head
  k_pool<<<G,256,0,stream>>>(hf,batch,gp,N);
  k_clf<<<(G*64+255)/256,256,0,stream>>>(gp,cW1,cb1,cW2,cb2,out,G);
}

// Round 8
// 548.392 us; speedup vs baseline: 1.1004x; 1.0013x over previous
//
#include <hip/hip_runtime.h>

// ---------------------------------------------------------------------------
// RGCN restructured: aggregate x[src] FIRST (per relation), then one GEMM
//   A = [Sn_rel0 | Sn_rel1 | x_self],  Wcat = [W0; W1; root]
// R4: CSR build via two-level counting sort (cache-resident random writes).
// R5: k_clf one wave per graph.
// R8: gather = staged-shfl indices (no dependent index loads, R6 lesson) +
//     per-segment uniform loops (no per-edge relation select, R7) +
//     reductions HOISTED out of the segment loop (R7's per-segment shfl_xor
//     forced vmcnt(0) drains every ~4 loads -> VALUBusy 56%) + 4-deep
//     unroll so 4 loads are in flight per wait.
// ---------------------------------------------------------------------------

typedef unsigned int uint;
typedef unsigned short ushort;

#define EPB 8192   // edges per block in count/partition kernels

__device__ __forceinline__ void fma4(float4& a, float s, const float4& w){
  a.x += s*w.x; a.y += s*w.y; a.z += s*w.z; a.w += s*w.w;
}
__device__ __forceinline__ uint bf1(float f){          // f32 -> bf16 (RNE)
  uint u = __float_as_uint(f);
  return (u + 0x7fffu + ((u>>16)&1u)) >> 16;
}
__device__ __forceinline__ uint bfpack2(float lo, float hi){
  return bf1(lo) | (bf1(hi)<<16);
}
__device__ __forceinline__ float2 bf2cvt(uint w){
  float2 r; r.x = __uint_as_float(w<<16); r.y = __uint_as_float(w & 0xffff0000u);
  return r;
}
__device__ __forceinline__ void bfacc(uint2 w, float4& s){
  s.x += __uint_as_float(w.x<<16);
  s.y += __uint_as_float(w.x & 0xffff0000u);
  s.z += __uint_as_float(w.y<<16);
  s.w += __uint_as_float(w.y & 0xffff0000u);
}
__device__ __forceinline__ void redf4(float4& a){
  a.x += __shfl_xor(a.x,16); a.x += __shfl_xor(a.x,32);
  a.y += __shfl_xor(a.y,16); a.y += __shfl_xor(a.y,32);
  a.z += __shfl_xor(a.z,16); a.z += __shfl_xor(a.z,32);
  a.w += __shfl_xor(a.w,16); a.w += __shfl_xor(a.w,32);
}

// --------------------- CSR build: two-level counting sort ------------------

__global__ __launch_bounds__(256) void k_count(const int* __restrict__ ei,
    int* __restrict__ bhist, int E){
  __shared__ int h[256];
  int t = threadIdx.x;
  h[t] = 0; __syncthreads();
  int base = blockIdx.x*EPB;
  for (int i=t; i<EPB; i+=256){
    int e = base+i;
    if (e < E) atomicAdd(&h[ei[E+e]>>9], 1);
  }
  __syncthreads();
  if (h[t]) atomicAdd(&bhist[t], h[t]);
}

__global__ __launch_bounds__(256) void k_bscan(const int* __restrict__ bhist,
    int* __restrict__ bbase, int* __restrict__ bcur){
  __shared__ int lds[256];
  int t = threadIdx.x;
  int v = bhist[t];
  lds[t] = v; __syncthreads();
  for (int off=1; off<256; off<<=1){
    int tmp = (t>=off)? lds[t-off]:0;
    __syncthreads();
    lds[t] += tmp;
    __syncthreads();
  }
  int excl = lds[t]-v;
  bbase[t] = excl; bcur[t] = excl;
  if (t==255) bbase[256] = excl+v;
}

// partition edges into bucket regions as packed (src<<10)|((dst&511)<<1|ty)
__global__ __launch_bounds__(256) void k_part(const int* __restrict__ ei,
    const int* __restrict__ et, int* __restrict__ bcur,
    uint* __restrict__ bk, int E){
  __shared__ int h[256];
  __shared__ int cur[256];
  int t = threadIdx.x;
  h[t] = 0; __syncthreads();
  int base = blockIdx.x*EPB;
  for (int i=t; i<EPB; i+=256){
    int e = base+i;
    if (e < E) atomicAdd(&h[ei[E+e]>>9], 1);
  }
  __syncthreads();
  int c = h[t];
  cur[t] = c ? atomicAdd(&bcur[t], c) : 0;
  __syncthreads();
  for (int i=t; i<EPB; i+=256){
    int e = base+i;
    if (e < E){
      int s = ei[e], d = ei[E+e], ty = et[e];
      int p = atomicAdd(&cur[d>>9], 1);
      bk[p] = ((uint)s<<10) | (uint)(((d&511)<<1) | ty);
    }
  }
}

// per-bucket fine sort: deg, pos (segment START), ssrc within 64KB window
__global__ __launch_bounds__(256) void k_csr(const uint* __restrict__ bk,
    const int* __restrict__ bbase, int* __restrict__ deg,
    int* __restrict__ pos, int* __restrict__ ssrc, int N){
  __shared__ int h[1024];
  __shared__ int cur[1024];
  __shared__ int ws[256];
  int b = blockIdx.x, t = threadIdx.x;
  int start = bbase[b], end = bbase[b+1];
  h[t]=0; h[256+t]=0; h[512+t]=0; h[768+t]=0;
  __syncthreads();
  for (int i=start+t; i<end; i+=256) atomicAdd(&h[bk[i]&1023], 1);
  __syncthreads();
  int c0=h[4*t], c1=h[4*t+1], c2=h[4*t+2], c3=h[4*t+3];
  int s = c0+c1+c2+c3;
  ws[t] = s; __syncthreads();
  for (int off=1; off<256; off<<=1){
    int tmp = (t>=off)? ws[t-off]:0;
    __syncthreads();
    ws[t] += tmp;
    __syncthreads();
  }
  int base0 = start + ws[t] - s;
  cur[4*t]   = base0;
  cur[4*t+1] = base0 + c0;
  cur[4*t+2] = base0 + c0 + c1;
  cur[4*t+3] = base0 + c0 + c1 + c2;
  int gk = b*1024 + 4*t;
  int nodeA = (b<<9) + 2*t, nodeB = nodeA + 1;
  if (nodeA < N){
    deg[gk]   = c0; deg[gk+1] = c1;
    pos[gk]   = base0; pos[gk+1] = base0 + c0;
  }
  if (nodeB < N){
    deg[gk+2] = c2; deg[gk+3] = c3;
    pos[gk+2] = base0 + c0 + c1; pos[gk+3] = base0 + c0 + c1 + c2;
  }
  __syncthreads();
  for (int i=start+t; i<end; i+=256){
    uint w = bk[i];
    int p = atomicAdd(&cur[w & 1023], 1);
    ssrc[p] = (int)(w >> 10);
  }
}

// ----------------------- gather (64-ch bf16 features) ---------------------
// Staged-shfl indices, per-segment uniform loop, NO internal reduction
// (accumulator stays un-reduced so the VMEM queue never drains mid-kernel).
// 16 lanes per 128B row (uint2 = 4 ch/lane), 4 edge groups, 4-deep unroll.
__device__ __forceinline__ void seg_sum64(const ushort* __restrict__ hp,
    const int* __restrict__ ssrc, int p, int d, int lane, int c4, int eg,
    float4& s){
  int j = 0;
  while (j < d){
    int take = d - j; if (take > 64) take = 64;
    int sv = (lane < take) ? ssrc[p + j + lane] : 0;
    int e = 0;
    for (; e+16 <= take; e += 16){
      int si0 = __shfl(sv, e+eg);
      int si1 = __shfl(sv, e+4+eg);
      int si2 = __shfl(sv, e+8+eg);
      int si3 = __shfl(sv, e+12+eg);
      uint2 w0 = *(const uint2*)(hp + (size_t)si0*64 + c4*4);
      uint2 w1 = *(const uint2*)(hp + (size_t)si1*64 + c4*4);
      uint2 w2 = *(const uint2*)(hp + (size_t)si2*64 + c4*4);
      uint2 w3 = *(const uint2*)(hp + (size_t)si3*64 + c4*4);
      bfacc(w0,s); bfacc(w1,s); bfacc(w2,s); bfacc(w3,s);
    }
    for (; e+4 <= take; e += 4){
      int si = __shfl(sv, e+eg);
      uint2 w = *(const uint2*)(hp + (size_t)si*64 + c4*4);
      bfacc(w,s);
    }
    if (e < take){
      int idx = e + eg;
      int si = __shfl(sv, idx < take ? idx : 0);
      uint2 w = {0u,0u};
      if (idx < take) w = *(const uint2*)(hp + (size_t)si*64 + c4*4);
      bfacc(w,s);
    }
    j += take;
  }
}

__global__ __launch_bounds__(256) void k_gather64(
    const ushort* __restrict__ hp, const int* __restrict__ deg,
    const int* __restrict__ pos, const int* __restrict__ ssrc,
    ushort* __restrict__ sn, int N)
{
  int lane = threadIdx.x & 63;
  int wid  = (blockIdx.x*256 + threadIdx.x) >> 6;
  int c4 = lane & 15, eg = lane >> 4;
  int nA = wid*2, nB = nA+1;
  if (nA >= N) return;
  int d0A = deg[2*nA], d1A = deg[2*nA+1];
  int p0A = pos[2*nA], p1A = pos[2*nA+1];
  int d0B = 0, d1B = 0, p0B = 0, p1B = 0;
  if (nB < N){ d0B = deg[2*nB]; d1B = deg[2*nB+1]; p0B = pos[2*nB]; p1B = pos[2*nB+1]; }

  float4 s0A={0,0,0,0}, s1A={0,0,0,0}, s0B={0,0,0,0}, s1B={0,0,0,0};
  seg_sum64(hp, ssrc, p0A, d0A, lane, c4, eg, s0A);
  seg_sum64(hp, ssrc, p1A, d1A, lane, c4, eg, s1A);
  seg_sum64(hp, ssrc, p0B, d0B, lane, c4, eg, s0B);
  seg_sum64(hp, ssrc, p1B, d1B, lane, c4, eg, s1B);

  // single reduction point (one VMEM drain per node-pair)
  redf4(s0A); redf4(s1A); redf4(s0B); redf4(s1B);

  float i0A = 1.f/(float)(d0A>1?d0A:1), i1A = 1.f/(float)(d1A>1?d1A:1);
  float i0B = 1.f/(float)(d0B>1?d0B:1), i1B = 1.f/(float)(d1B>1?d1B:1);
  s0A.x*=i0A; s0A.y*=i0A; s0A.z*=i0A; s0A.w*=i0A;
  s1A.x*=i1A; s1A.y*=i1A; s1A.z*=i1A; s1A.w*=i1A;
  s0B.x*=i0B; s0B.y*=i0B; s0B.z*=i0B; s0B.w*=i0B;
  s1B.x*=i1B; s1B.y*=i1B; s1B.z*=i1B; s1B.w*=i1B;
  // lanes 0-15: (A,rel0) 16-31: (A,rel1) 32-47: (B,rel0) 48-63: (B,rel1)
  float4 v = (lane < 32) ? ((lane < 16) ? s0A : s1A)
                         : ((lane < 48) ? s0B : s1B);
  int n   = (lane < 32) ? nA : nB;
  int rel = (lane >> 4) & 1;
  if (n < N){
    uint2 pkt; pkt.x = bfpack2(v.x, v.y); pkt.y = bfpack2(v.z, v.w);
    *(uint2*)(sn + (size_t)n*128 + rel*64 + c4*4) = pkt;
  }
}

// ------------------------ gather (8-ch f32 input x) -----------------------
__device__ __forceinline__ void seg_sum8(const float* __restrict__ xp,
    const int* __restrict__ ssrc, int p, int d, int lane, int c, int eg,
    float& s){
  int j = 0;
  while (j < d){
    int take = d - j; if (take > 64) take = 64;
    int sv = (lane < take) ? ssrc[p + j + lane] : 0;
    int e = 0;
    for (; e+32 <= take; e += 32){
      int si0 = __shfl(sv, e+eg);
      int si1 = __shfl(sv, e+8+eg);
      int si2 = __shfl(sv, e+16+eg);
      int si3 = __shfl(sv, e+24+eg);
      float v0 = xp[(size_t)si0*8 + c];
      float v1 = xp[(size_t)si1*8 + c];
      float v2 = xp[(size_t)si2*8 + c];
      float v3 = xp[(size_t)si3*8 + c];
      s += v0; s += v1; s += v2; s += v3;
    }
    for (; e+8 <= take; e += 8){
      int si = __shfl(sv, e+eg);
      s += xp[(size_t)si*8 + c];
    }
    if (e < take){
      int idx = e + eg;
      int si = __shfl(sv, idx < take ? idx : 0);
      float v = 0.f;
      if (idx < take) v = xp[(size_t)si*8 + c];
      s += v;
    }
    j += take;
  }
}

__global__ __launch_bounds__(256) void k_gather8(
    const float* __restrict__ xp, const int* __restrict__ deg,
    const int* __restrict__ pos, const int* __restrict__ ssrc,
    float* __restrict__ sn1, int N)
{
  int lane = threadIdx.x & 63;
  int wid  = (blockIdx.x*256 + threadIdx.x) >> 6;
  int c = lane & 7, eg = lane >> 3;
  int nA = wid*2, nB = nA+1;
  if (nA >= N) return;
  int d0A = deg[2*nA], d1A = deg[2*nA+1];
  int p0A = pos[2*nA], p1A = pos[2*nA+1];
  int d0B = 0, d1B = 0, p0B = 0, p1B = 0;
  if (nB < N){ d0B = deg[2*nB]; d1B = deg[2*nB+1]; p0B = pos[2*nB]; p1B = pos[2*nB+1]; }

  float s0A=0.f, s1A=0.f, s0B=0.f, s1B=0.f;
  seg_sum8(xp, ssrc, p0A, d0A, lane, c, eg, s0A);
  seg_sum8(xp, ssrc, p1A, d1A, lane, c, eg, s1A);
  seg_sum8(xp, ssrc, p0B, d0B, lane, c, eg, s0B);
  seg_sum8(xp, ssrc, p1B, d1B, lane, c, eg, s1B);

  #pragma unroll
  for (int off=8; off<64; off<<=1){
    s0A += __shfl_xor(s0A, off); s1A += __shfl_xor(s1A, off);
    s0B += __shfl_xor(s0B, off); s1B += __shfl_xor(s1B, off);
  }
  s0A *= 1.f/(float)(d0A>1?d0A:1);  s1A *= 1.f/(float)(d1A>1?d1A:1);
  s0B *= 1.f/(float)(d0B>1?d0B:1);  s1B *= 1.f/(float)(d1B>1?d1B:1);
  // lanes 0-7:(A,r0) 8-15:(A,r1) 16-23:(B,r0) 24-31:(B,r1)
  if (lane < 32){
    float v = (lane < 16) ? ((lane & 8) ? s1A : s0A)
                          : ((lane & 8) ? s1B : s0B);
    int n = (lane < 16) ? nA : nB;
    if (n < N) sn1[(size_t)n*16 + (lane & 15)] = v;
  }
}

// ----------------------- GEMM layers 2/3 (K=192) --------------------------
#define AST 196
template<int RELU, int OUTBF>
__global__ __launch_bounds__(256) void k_mm192(
    const ushort* __restrict__ sn,   // [N,128] bf16 (rel0|rel1 means)
    const ushort* __restrict__ hp,   // [N,64]  bf16 self
    const float* __restrict__ Wl,    // [128,64]
    const float* __restrict__ rootp, // [64,64]
    const float* __restrict__ bias, void* __restrict__ hout_, int N)
{
  __shared__ float A[64*AST];
  int t = threadIdx.x;
  int nb = blockIdx.x*64;
  #pragma unroll
  for (int k=0;k<4;++k){
    int q = k*256 + t;
    int nl = q>>4, off = q&15;
    int n = nb + nl;
    uint4 w = {0,0,0,0};
    if (n < N) w = *(const uint4*)(sn + (size_t)n*128 + off*8);
    float2 a = bf2cvt(w.x), b = bf2cvt(w.y), c = bf2cvt(w.z), d = bf2cvt(w.w);
    float* dst = &A[nl*AST + off*8];
    float4 lo = {a.x,a.y,b.x,b.y}, hi = {c.x,c.y,d.x,d.y};
    *(float4*)dst = lo; *(float4*)(dst+4) = hi;
  }
  #pragma unroll
  for (int k=0;k<2;++k){
    int q = k*256 + t;
    int nl = q>>3, off = q&7;
    int n = nb + nl;
    uint4 w = {0,0,0,0};
    if (n < N) w = *(const uint4*)(hp + (size_t)n*64 + off*8);
    float2 a = bf2cvt(w.x), b = bf2cvt(w.y), c = bf2cvt(w.z), d = bf2cvt(w.w);
    float* dst = &A[nl*AST + 128 + off*8];
    float4 lo = {a.x,a.y,b.x,b.y}, hi = {c.x,c.y,d.x,d.y};
    *(float4*)dst = lo; *(float4*)(dst+4) = hi;
  }
  __syncthreads();
  int o0 = (t&15)*4, r0 = (t>>4)*4;
  float4 b4 = *(const float4*)(bias+o0);
  float4 a0=b4,a1=b4,a2=b4,a3=b4;
  const float* Ab = &A[r0*AST];
  #pragma unroll 4
  for (int i=0;i<128;++i){
    float4 w = *(const float4*)(Wl + i*64 + o0);
    fma4(a0, Ab[i],       w); fma4(a1, Ab[AST+i],   w);
    fma4(a2, Ab[2*AST+i], w); fma4(a3, Ab[3*AST+i], w);
  }
  #pragma unroll 4
  for (int i=0;i<64;++i){
    float4 w = *(const float4*)(rootp + i*64 + o0);
    fma4(a0, Ab[128+i],       w); fma4(a1, Ab[AST+128+i],   w);
    fma4(a2, Ab[2*AST+128+i], w); fma4(a3, Ab[3*AST+128+i], w);
  }
  float4 accs[4] = {a0,a1,a2,a3};
  #pragma unroll
  for (int q=0;q<4;++q){
    int n = nb + r0 + q;
    if (n < N){
      float4 r = accs[q];
      if (RELU){ r.x=fmaxf(r.x,0.f); r.y=fmaxf(r.y,0.f); r.z=fmaxf(r.z,0.f); r.w=fmaxf(r.w,0.f); }
      if (OUTBF){
        uint2 p; p.x = bfpack2(r.x,r.y); p.y = bfpack2(r.z,r.w);
        *(uint2*)((ushort*)hout_ + (size_t)n*64 + o0) = p;
      } else {
        *(float4*)((float*)hout_ + (size_t)n*64 + o0) = r;
      }
    }
  }
}

// -------------------------- GEMM layer 1 (K=24) ---------------------------
__global__ __launch_bounds__(256) void k_mm24(
    const float* __restrict__ sn1,   // [N,16] f32
    const float* __restrict__ xp,    // [N,8] f32 self
    const float* __restrict__ Wl,    // [16,64]
    const float* __restrict__ rootp, // [8,64]
    const float* __restrict__ bias, ushort* __restrict__ hout, int N)
{
  __shared__ float A[64*25];
  int t = threadIdx.x;
  int nb = blockIdx.x*64;
  #pragma unroll
  for (int k=0;k<4;++k){
    int q = k*256 + t;
    int nl = q>>4, c = q&15;
    int n = nb + nl;
    A[nl*25 + c] = (n < N) ? sn1[(size_t)n*16 + c] : 0.f;
  }
  #pragma unroll
  for (int k=0;k<2;++k){
    int q = k*256 + t;
    int nl = q>>3, c = q&7;
    int n = nb + nl;
    A[nl*25 + 16 + c] = (n < N) ? xp[(size_t)n*8 + c] : 0.f;
  }
  __syncthreads();
  int o0=(t&15)*4, r0=(t>>4)*4;
  float4 b4 = *(const float4*)(bias+o0);
  float4 a0=b4,a1=b4,a2=b4,a3=b4;
  const float* Ab=&A[r0*25];
  #pragma unroll
  for (int i=0;i<16;++i){
    float4 w=*(const float4*)(Wl+i*64+o0);
    fma4(a0,Ab[i],w); fma4(a1,Ab[25+i],w); fma4(a2,Ab[50+i],w); fma4(a3,Ab[75+i],w);
  }
  #pragma unroll
  for (int i=0;i<8;++i){
    float4 w=*(const float4*)(rootp+i*64+o0);
    fma4(a0,Ab[16+i],w); fma4(a1,Ab[41+i],w); fma4(a2,Ab[66+i],w); fma4(a3,Ab[91+i],w);
  }
  float4 accs[4]={a0,a1,a2,a3};
  #pragma unroll
  for (int q=0;q<4;++q){
    int n = nb + r0 + q;
    if (n < N){
      float4 r = accs[q];
      r.x=fmaxf(r.x,0.f); r.y=fmaxf(r.y,0.f); r.z=fmaxf(r.z,0.f); r.w=fmaxf(r.w,0.f);
      uint2 p; p.x = bfpack2(r.x,r.y); p.y = bfpack2(r.z,r.w);
      *(uint2*)(hout + (size_t)n*64 + o0) = p;
    }
  }
}

// ------------------------------- pool + MLP -------------------------------

__device__ __forceinline__ int lowerb(const int* __restrict__ b, int n, int key){
  int lo=0, hi=n;
  while (lo<hi){ int mid=(lo+hi)>>1; if (b[mid]<key) lo=mid+1; else hi=mid; }
  return lo;
}

__global__ __launch_bounds__(256) void k_pool(const float* __restrict__ h,
    const int* __restrict__ batch, float* __restrict__ gp, int N){
  __shared__ float red[256];
  int g=blockIdx.x, t=threadIdx.x;
  int start=lowerb(batch,N,g), end=lowerb(batch,N,g+1);
  int c=t&63, p=t>>6;
  float s=0.f;
  for (int n=start+p; n<end; n+=4) s += h[(size_t)n*64+c];
  red[t]=s; __syncthreads();
  if (t<64) gp[g*64+c] = red[c]+red[64+c]+red[128+c]+red[192+c];
}

// one wave per graph: lane l -> hidden j=l&31, half=l>>5
__global__ __launch_bounds__(256) void k_clf(const float* __restrict__ gp,
    const float* __restrict__ cW1, const float* __restrict__ cb1,
    const float* __restrict__ cW2, const float* __restrict__ cb2,
    float* __restrict__ out, int G){
  int lane = threadIdx.x & 63;
  int g = (blockIdx.x*256 + threadIdx.x) >> 6;
  if (g >= G) return;
  int j = lane & 31, half = lane >> 5;
  const float* gv = gp + (size_t)g*64 + half*32;
  const float* Wc = cW1 + half*32*32 + j;
  float s = 0.f;
  #pragma unroll 8
  for (int i=0;i<32;++i) s += gv[i] * Wc[i*32];
  s += __shfl_xor(s, 32);
  s = fmaxf(s + cb1[j], 0.f) * cW2[j];
  s += __shfl_xor(s, 1);  s += __shfl_xor(s, 2);
  s += __shfl_xor(s, 4);  s += __shfl_xor(s, 8);
  s += __shfl_xor(s, 16);
  if (lane == 0) out[g] = s + cb2[0];
}

extern "C" void kernel_launch(void* const* d_in, const int* in_sizes, int n_in,
                              void* d_out, int out_size, void* d_ws, size_t ws_size,
                              hipStream_t stream){
  const float* x     = (const float*)d_in[0];
  const int*   ei    = (const int*)d_in[1];
  const int*   et    = (const int*)d_in[2];
  const int*   batch = (const int*)d_in[3];
  const float* W1    = (const float*)d_in[4];
  const float* root1 = (const float*)d_in[5];
  const float* b1    = (const float*)d_in[6];
  const float* W2    = (const float*)d_in[7];
  const float* root2 = (const float*)d_in[8];
  const float* b2    = (const float*)d_in[9];
  const float* W3    = (const float*)d_in[10];
  const float* root3 = (const float*)d_in[11];
  const float* b3    = (const float*)d_in[12];
  const float* cW1   = (const float*)d_in[13];
  const float* cb1   = (const float*)d_in[14];
  const float* cW2   = (const float*)d_in[15];
  const float* cb2   = (const float*)d_in[16];
  float* out = (float*)d_out;
  (void)n_in; (void)ws_size;

  int N = in_sizes[0]/8;      // 100000
  int E = in_sizes[2];        // 3200000
  int G = out_size;           // 256
  int M = 2*N;

  char* w = (char*)d_ws;
  auto alloc=[&](size_t bytes)->char*{ char* p=w; w += (bytes+255)&~(size_t)255; return p; };
  int*    bhist = (int*)alloc(256*4);
  int*    bbase = (int*)alloc(257*4);
  int*    bcur  = (int*)alloc(256*4);
  int*    ssrc  = (int*)alloc((size_t)E*4);
  int*    deg   = (int*)alloc((size_t)M*4);
  int*    pos   = (int*)alloc((size_t)M*4);
  ushort* h1    = (ushort*)alloc((size_t)N*64*2);
  ushort* snU   = (ushort*)alloc((size_t)N*128*2);
  ushort* h2    = (ushort*)alloc((size_t)N*64*2);  // bk aliases this
  float*  gp    = (float*)alloc((size_t)G*64*4);
  uint*   bk    = (uint*)h2;                       // dead before h2 is written
  float*  sn1   = (float*)snU;                     // [N,16] f32, dead after k_mm24
  float*  hf    = (float*)ssrc;                    // [N,64] f32 spans ssrc+deg+pos+h1, all dead at layer-3 GEMM

  hipMemsetAsync(bhist, 0, 256*4, stream);
  int nbE = (E + EPB - 1)/EPB;
  k_count<<<nbE,256,0,stream>>>(ei,bhist,E);
  k_bscan<<<1,256,0,stream>>>(bhist,bbase,bcur);
  k_part <<<nbE,256,0,stream>>>(ei,et,bcur,bk,E);
  k_csr  <<<256,256,0,stream>>>(bk,bbase,deg,pos,ssrc,N);

  int gb = (((N+1)/2) + 3) / 4;     // waves = ceil(N/2), 4 waves/block
  int nbk = (N+63)/64;
  // layer 1
  k_gather8 <<<gb,256,0,stream>>>(x,deg,pos,ssrc,sn1,N);
  k_mm24    <<<nbk,256,0,stream>>>(sn1,x,W1,root1,b1,h1,N);
  // layer 2
  k_gather64<<<gb,256,0,stream>>>(h1,deg,pos,ssrc,snU,N);
  k_mm192<1,1><<<nbk,256,0,stream>>>(snU,h1,W2,root2,b2,h2,N);
  // layer 3
  k_gather64<<<gb,256,0,stream>>>(h2,deg,pos,ssrc,snU,N);
  k_mm192<0,0><<<nbk,256,0,stream>>>(snU,h2,W3,root3,b3,hf,N);
  // pool + head
  k_pool<<<G,256,0,stream>>>(hf,batch,gp,N);
  k_clf<<<(G*64+255)/256,256,0,stream>>>(gp,cW1,cb1,cW2,cb2,out,G);
}

// Round 9
// 482.909 us; speedup vs baseline: 1.2496x; 1.1356x over previous
//
#include <hip/hip_runtime.h>

// ---------------------------------------------------------------------------
// RGCN restructured: aggregate x[src] FIRST (per relation), then one GEMM
//   A = [Sn_rel0 | Sn_rel1 | x_self],  Wcat = [W0; W1; root]
// R4: CSR build via two-level counting sort (cache-resident random writes).
// R5: k_clf one wave per graph.
// R9: gathers reverted to R5 structure (indices for BOTH nodes staged
//     up-front -> one continuous feature-load stream, one drain/pair;
//     R6-R8 all stalled on per-segment index-load vmcnt waits) with a
//     cheaper select (tot + rel1-only accumulators, s0 = tot - s1).
//     k_mm192 -> MFMA (bf16 inputs already in memory; weights pre-packed
//     bf16 transposed). Layouts per verified notes: A[m=lane&15][k=quad*8+j],
//     D col=lane&15 row=quad*4+reg.
// ---------------------------------------------------------------------------

typedef unsigned int uint;
typedef unsigned short ushort;
typedef __attribute__((ext_vector_type(8))) short bf16x8;
typedef __attribute__((ext_vector_type(4))) float f32x4;

#define EPB 8192   // edges per block in count/partition kernels

__device__ __forceinline__ void fma4(float4& a, float s, const float4& w){
  a.x += s*w.x; a.y += s*w.y; a.z += s*w.z; a.w += s*w.w;
}
__device__ __forceinline__ uint bf1(float f){          // f32 -> bf16 (RNE)
  uint u = __float_as_uint(f);
  return (u + 0x7fffu + ((u>>16)&1u)) >> 16;
}
__device__ __forceinline__ uint bfpack2(float lo, float hi){
  return bf1(lo) | (bf1(hi)<<16);
}
__device__ __forceinline__ float4 bf4cvt(uint2 w){
  float4 r;
  r.x = __uint_as_float(w.x<<16);
  r.y = __uint_as_float(w.x & 0xffff0000u);
  r.z = __uint_as_float(w.y<<16);
  r.w = __uint_as_float(w.y & 0xffff0000u);
  return r;
}
__device__ __forceinline__ float2 bf2cvt(uint w){
  float2 r; r.x = __uint_as_float(w<<16); r.y = __uint_as_float(w & 0xffff0000u);
  return r;
}
__device__ __forceinline__ void addf4(float4& a, const float4& f){
  a.x += f.x; a.y += f.y; a.z += f.z; a.w += f.w;
}
__device__ __forceinline__ void selacc(float4& s, const float4& f, bool take){
  s.x += take ? f.x : 0.f;
  s.y += take ? f.y : 0.f;
  s.z += take ? f.z : 0.f;
  s.w += take ? f.w : 0.f;
}
__device__ __forceinline__ void redf4(float4& a){
  a.x += __shfl_xor(a.x,16); a.x += __shfl_xor(a.x,32);
  a.y += __shfl_xor(a.y,16); a.y += __shfl_xor(a.y,32);
  a.z += __shfl_xor(a.z,16); a.z += __shfl_xor(a.z,32);
  a.w += __shfl_xor(a.w,16); a.w += __shfl_xor(a.w,32);
}

// --------------------- CSR build: two-level counting sort ------------------

__global__ __launch_bounds__(256) void k_count(const int* __restrict__ ei,
    int* __restrict__ bhist, int E){
  __shared__ int h[256];
  int t = threadIdx.x;
  h[t] = 0; __syncthreads();
  int base = blockIdx.x*EPB;
  for (int i=t; i<EPB; i+=256){
    int e = base+i;
    if (e < E) atomicAdd(&h[ei[E+e]>>9], 1);
  }
  __syncthreads();
  if (h[t]) atomicAdd(&bhist[t], h[t]);
}

__global__ __launch_bounds__(256) void k_bscan(const int* __restrict__ bhist,
    int* __restrict__ bbase, int* __restrict__ bcur){
  __shared__ int lds[256];
  int t = threadIdx.x;
  int v = bhist[t];
  lds[t] = v; __syncthreads();
  for (int off=1; off<256; off<<=1){
    int tmp = (t>=off)? lds[t-off]:0;
    __syncthreads();
    lds[t] += tmp;
    __syncthreads();
  }
  int excl = lds[t]-v;
  bbase[t] = excl; bcur[t] = excl;
  if (t==255) bbase[256] = excl+v;
}

// partition edges into bucket regions as packed (src<<10)|((dst&511)<<1|ty)
__global__ __launch_bounds__(256) void k_part(const int* __restrict__ ei,
    const int* __restrict__ et, int* __restrict__ bcur,
    uint* __restrict__ bk, int E){
  __shared__ int h[256];
  __shared__ int cur[256];
  int t = threadIdx.x;
  h[t] = 0; __syncthreads();
  int base = blockIdx.x*EPB;
  for (int i=t; i<EPB; i+=256){
    int e = base+i;
    if (e < E) atomicAdd(&h[ei[E+e]>>9], 1);
  }
  __syncthreads();
  int c = h[t];
  cur[t] = c ? atomicAdd(&bcur[t], c) : 0;
  __syncthreads();
  for (int i=t; i<EPB; i+=256){
    int e = base+i;
    if (e < E){
      int s = ei[e], d = ei[E+e], ty = et[e];
      int p = atomicAdd(&cur[d>>9], 1);
      bk[p] = ((uint)s<<10) | (uint)(((d&511)<<1) | ty);
    }
  }
}

// per-bucket fine sort: deg, pos (segment START), ssrc within 64KB window
__global__ __launch_bounds__(256) void k_csr(const uint* __restrict__ bk,
    const int* __restrict__ bbase, int* __restrict__ deg,
    int* __restrict__ pos, int* __restrict__ ssrc, int N){
  __shared__ int h[1024];
  __shared__ int cur[1024];
  __shared__ int ws[256];
  int b = blockIdx.x, t = threadIdx.x;
  int start = bbase[b], end = bbase[b+1];
  h[t]=0; h[256+t]=0; h[512+t]=0; h[768+t]=0;
  __syncthreads();
  for (int i=start+t; i<end; i+=256) atomicAdd(&h[bk[i]&1023], 1);
  __syncthreads();
  int c0=h[4*t], c1=h[4*t+1], c2=h[4*t+2], c3=h[4*t+3];
  int s = c0+c1+c2+c3;
  ws[t] = s; __syncthreads();
  for (int off=1; off<256; off<<=1){
    int tmp = (t>=off)? ws[t-off]:0;
    __syncthreads();
    ws[t] += tmp;
    __syncthreads();
  }
  int base0 = start + ws[t] - s;
  cur[4*t]   = base0;
  cur[4*t+1] = base0 + c0;
  cur[4*t+2] = base0 + c0 + c1;
  cur[4*t+3] = base0 + c0 + c1 + c2;
  int gk = b*1024 + 4*t;
  int nodeA = (b<<9) + 2*t, nodeB = nodeA + 1;
  if (nodeA < N){
    deg[gk]   = c0; deg[gk+1] = c1;
    pos[gk]   = base0; pos[gk+1] = base0 + c0;
  }
  if (nodeB < N){
    deg[gk+2] = c2; deg[gk+3] = c3;
    pos[gk+2] = base0 + c0 + c1; pos[gk+3] = base0 + c0 + c1 + c2;
  }
  __syncthreads();
  for (int i=start+t; i<end; i+=256){
    uint w = bk[i];
    int p = atomicAdd(&cur[w & 1023], 1);
    ssrc[p] = (int)(w >> 10);
  }
}

// ----------------------- gather (64-ch bf16 features) ---------------------
// R5 structure: one wave = 2 nodes; merged relation stream per node
// (contiguous in CSR); indices for BOTH nodes staged up-front each 64-edge
// chunk -> continuous feature-load stream, ~one vmcnt drain per pair.
// Select cost cut: tot (all edges) + s1 (rel1 only); s0 = tot - s1.
__global__ __launch_bounds__(256) void k_gather64(
    const ushort* __restrict__ hp, const int* __restrict__ deg,
    const int* __restrict__ pos, const int* __restrict__ ssrc,
    ushort* __restrict__ sn, int N)
{
  int lane = threadIdx.x & 63;
  int wid  = (blockIdx.x*256 + threadIdx.x) >> 6;
  int c4 = lane & 15, eg = lane >> 4;
  int nA = wid*2, nB = nA+1;
  if (nA >= N) return;
  int d0A = deg[2*nA], d1A = deg[2*nA+1];
  int pA  = pos[2*nA];
  int cA  = d0A + d1A;
  int d0B = 0, d1B = 0, pB = 0, cB = 0;
  if (nB < N){ d0B = deg[2*nB]; d1B = deg[2*nB+1]; pB = pos[2*nB]; cB = d0B+d1B; }

  float4 totA={0,0,0,0}, s1A={0,0,0,0}, totB={0,0,0,0}, s1B={0,0,0,0};
  int jA = 0, jB = 0;
  while (jA < cA || jB < cB){
    int tA = cA - jA; if (tA > 64) tA = 64;
    int tB = cB - jB; if (tB > 64) tB = 64;
    int svA = (lane < tA) ? ssrc[pA + jA + lane] : 0;
    int svB = (lane < tB) ? ssrc[pB + jB + lane] : 0;
    int mt = tA > tB ? tA : tB;
    for (int e = 0; e < mt; e += 4){
      int idx = e + eg;
      int siA = __shfl(svA, idx), siB = __shfl(svB, idx);
      uint2 wA = {0u,0u}, wB = {0u,0u};
      if (idx < tA) wA = *(const uint2*)(hp + (size_t)siA*64 + c4*4);
      if (idx < tB) wB = *(const uint2*)(hp + (size_t)siB*64 + c4*4);
      float4 fA = bf4cvt(wA), fB = bf4cvt(wB);
      addf4(totA, fA);  selacc(s1A, fA, (jA + idx) >= d0A);
      addf4(totB, fB);  selacc(s1B, fB, (jB + idx) >= d0B);
    }
    jA += tA; jB += tB;
  }
  float4 s0A = {totA.x-s1A.x, totA.y-s1A.y, totA.z-s1A.z, totA.w-s1A.w};
  float4 s0B = {totB.x-s1B.x, totB.y-s1B.y, totB.z-s1B.z, totB.w-s1B.w};
  redf4(s0A); redf4(s1A); redf4(s0B); redf4(s1B);
  float i0A = 1.f/(float)(d0A>1?d0A:1), i1A = 1.f/(float)(d1A>1?d1A:1);
  float i0B = 1.f/(float)(d0B>1?d0B:1), i1B = 1.f/(float)(d1B>1?d1B:1);
  s0A.x*=i0A; s0A.y*=i0A; s0A.z*=i0A; s0A.w*=i0A;
  s1A.x*=i1A; s1A.y*=i1A; s1A.z*=i1A; s1A.w*=i1A;
  s0B.x*=i0B; s0B.y*=i0B; s0B.z*=i0B; s0B.w*=i0B;
  s1B.x*=i1B; s1B.y*=i1B; s1B.z*=i1B; s1B.w*=i1B;
  // lanes 0-15: (A,rel0) 16-31: (A,rel1) 32-47: (B,rel0) 48-63: (B,rel1)
  float4 v = (lane < 32) ? ((lane < 16) ? s0A : s1A)
                         : ((lane < 48) ? s0B : s1B);
  int n   = (lane < 32) ? nA : nB;
  int rel = (lane >> 4) & 1;
  if (n < N){
    uint2 pkt; pkt.x = bfpack2(v.x, v.y); pkt.y = bfpack2(v.z, v.w);
    *(uint2*)(sn + (size_t)n*128 + rel*64 + c4*4) = pkt;
  }
}

// ------------------------ gather (8-ch f32 input x) -----------------------
__global__ __launch_bounds__(256) void k_gather8(
    const float* __restrict__ xp, const int* __restrict__ deg,
    const int* __restrict__ pos, const int* __restrict__ ssrc,
    float* __restrict__ sn1, int N)
{
  int lane = threadIdx.x & 63;
  int wid  = (blockIdx.x*256 + threadIdx.x) >> 6;
  int c = lane & 7, eg = lane >> 3;
  int nA = wid*2, nB = nA+1;
  if (nA >= N) return;
  int d0A = deg[2*nA], d1A = deg[2*nA+1];
  int pA  = pos[2*nA];
  int cA  = d0A + d1A;
  int d0B = 0, d1B = 0, pB = 0, cB = 0;
  if (nB < N){ d0B = deg[2*nB]; d1B = deg[2*nB+1]; pB = pos[2*nB]; cB = d0B+d1B; }

  float totA=0.f, s1A=0.f, totB=0.f, s1B=0.f;
  int jA = 0, jB = 0;
  while (jA < cA || jB < cB){
    int tA = cA - jA; if (tA > 64) tA = 64;
    int tB = cB - jB; if (tB > 64) tB = 64;
    int svA = (lane < tA) ? ssrc[pA + jA + lane] : 0;
    int svB = (lane < tB) ? ssrc[pB + jB + lane] : 0;
    int mt = tA > tB ? tA : tB;
    for (int e = 0; e < mt; e += 8){
      int idx = e + eg;
      int siA = __shfl(svA, idx), siB = __shfl(svB, idx);
      float vA = 0.f, vB = 0.f;
      if (idx < tA) vA = xp[(size_t)siA*8 + c];
      if (idx < tB) vB = xp[(size_t)siB*8 + c];
      totA += vA;  s1A += ((jA + idx) >= d0A) ? vA : 0.f;
      totB += vB;  s1B += ((jB + idx) >= d0B) ? vB : 0.f;
    }
    jA += tA; jB += tB;
  }
  float s0A = totA - s1A, s0B = totB - s1B;
  #pragma unroll
  for (int off=8; off<64; off<<=1){
    s0A += __shfl_xor(s0A, off); s1A += __shfl_xor(s1A, off);
    s0B += __shfl_xor(s0B, off); s1B += __shfl_xor(s1B, off);
  }
  s0A *= 1.f/(float)(d0A>1?d0A:1);  s1A *= 1.f/(float)(d1A>1?d1A:1);
  s0B *= 1.f/(float)(d0B>1?d0B:1);  s1B *= 1.f/(float)(d1B>1?d1B:1);
  // lanes 0-7:(A,r0) 8-15:(A,r1) 16-23:(B,r0) 24-31:(B,r1)
  if (lane < 32){
    float v = (lane < 16) ? ((lane & 8) ? s1A : s0A)
                          : ((lane & 8) ? s1B : s0B);
    int n = (lane < 16) ? nA : nB;
    if (n < N) sn1[(size_t)n*16 + (lane & 15)] = v;
  }
}

// ------------------- weight pack: Wcat -> bf16 WT[n][k] -------------------
__global__ __launch_bounds__(256) void k_wprep(const float* __restrict__ Wl,
    const float* __restrict__ rootp, ushort* __restrict__ wt){
  int t = threadIdx.x;
  for (int i = t; i < 64*192; i += 256){
    int n = i / 192, k = i - n*192;
    float v = (k < 128) ? Wl[k*64 + n] : rootp[(k-128)*64 + n];
    wt[i] = (ushort)bf1(v);
  }
}

// ----------------- GEMM layers 2/3 (K=192) via MFMA -----------------------
// wave = 16-node strip x 64 outputs; A direct from global (bf16 rows),
// B from WT[n][k] bf16 (L1-hot). A[m=lane&15][k=quad*8+j]; D col=lane&15,
// row=quad*4+reg (verified layouts).
template<int RELU, int OUTBF>
__global__ __launch_bounds__(256) void k_mm192m(
    const ushort* __restrict__ sn,   // [N,128] bf16 (rel0|rel1 means)
    const ushort* __restrict__ hp,   // [N,64]  bf16 self
    const ushort* __restrict__ wt,   // [64,192] bf16 = [Wcat]^T
    const float* __restrict__ bias, void* __restrict__ hout_, int N)
{
  int t = threadIdx.x, lane = t & 63, w = t >> 6;
  int quad = lane >> 4, l15 = lane & 15;
  int nb = blockIdx.x * 64;
  int node = nb + w*16 + l15;
  int ncl = node < N ? node : N-1;
  const ushort* arow_sn = sn + (size_t)ncl*128 + quad*8;
  const ushort* arow_hp = hp + (size_t)ncl*64  + quad*8;

  f32x4 acc0={0,0,0,0}, acc1={0,0,0,0}, acc2={0,0,0,0}, acc3={0,0,0,0};
  #pragma unroll
  for (int ks = 0; ks < 6; ++ks){
    bf16x8 a = (ks < 4) ? *(const bf16x8*)(arow_sn + ks*32)
                        : *(const bf16x8*)(arow_hp + (ks-4)*32);
    const ushort* wk = wt + (size_t)l15*192 + ks*32 + quad*8;
    bf16x8 b0 = *(const bf16x8*)(wk);
    bf16x8 b1 = *(const bf16x8*)(wk + 16*192);
    bf16x8 b2 = *(const bf16x8*)(wk + 32*192);
    bf16x8 b3 = *(const bf16x8*)(wk + 48*192);
    acc0 = __builtin_amdgcn_mfma_f32_16x16x32_bf16(a, b0, acc0, 0,0,0);
    acc1 = __builtin_amdgcn_mfma_f32_16x16x32_bf16(a, b1, acc1, 0,0,0);
    acc2 = __builtin_amdgcn_mfma_f32_16x16x32_bf16(a, b2, acc2, 0,0,0);
    acc3 = __builtin_amdgcn_mfma_f32_16x16x32_bf16(a, b3, acc3, 0,0,0);
  }
  f32x4 accs[4] = {acc0, acc1, acc2, acc3};
  #pragma unroll
  for (int tt = 0; tt < 4; ++tt){
    int n = tt*16 + l15;                 // output channel
    float bv = bias[n];
    #pragma unroll
    for (int i = 0; i < 4; ++i){
      int nd = nb + w*16 + quad*4 + i;   // node (D row)
      if (nd < N){
        float v = accs[tt][i] + bv;
        if (RELU) v = fmaxf(v, 0.f);
        if (OUTBF) ((ushort*)hout_)[(size_t)nd*64 + n] = (ushort)bf1(v);
        else       ((float*)hout_)[(size_t)nd*64 + n] = v;
      }
    }
  }
}

// -------------------------- GEMM layer 1 (K=24) ---------------------------
__global__ __launch_bounds__(256) void k_mm24(
    const float* __restrict__ sn1,   // [N,16] f32
    const float* __restrict__ xp,    // [N,8] f32 self
    const float* __restrict__ Wl,    // [16,64]
    const float* __restrict__ rootp, // [8,64]
    const float* __restrict__ bias, ushort* __restrict__ hout, int N)
{
  __shared__ float A[64*25];
  int t = threadIdx.x;
  int nb = blockIdx.x*64;
  #pragma unroll
  for (int k=0;k<4;++k){
    int q = k*256 + t;
    int nl = q>>4, c = q&15;
    int n = nb + nl;
    A[nl*25 + c] = (n < N) ? sn1[(size_t)n*16 + c] : 0.f;
  }
  #pragma unroll
  for (int k=0;k<2;++k){
    int q = k*256 + t;
    int nl = q>>3, c = q&7;
    int n = nb + nl;
    A[nl*25 + 16 + c] = (n < N) ? xp[(size_t)n*8 + c] : 0.f;
  }
  __syncthreads();
  int o0=(t&15)*4, r0=(t>>4)*4;
  float4 b4 = *(const float4*)(bias+o0);
  float4 a0=b4,a1=b4,a2=b4,a3=b4;
  const float* Ab=&A[r0*25];
  #pragma unroll
  for (int i=0;i<16;++i){
    float4 w=*(const float4*)(Wl+i*64+o0);
    fma4(a0,Ab[i],w); fma4(a1,Ab[25+i],w); fma4(a2,Ab[50+i],w); fma4(a3,Ab[75+i],w);
  }
  #pragma unroll
  for (int i=0;i<8;++i){
    float4 w=*(const float4*)(rootp+i*64+o0);
    fma4(a0,Ab[16+i],w); fma4(a1,Ab[41+i],w); fma4(a2,Ab[66+i],w); fma4(a3,Ab[91+i],w);
  }
  float4 accs[4]={a0,a1,a2,a3};
  #pragma unroll
  for (int q=0;q<4;++q){
    int n = nb + r0 + q;
    if (n < N){
      float4 r = accs[q];
      r.x=fmaxf(r.x,0.f); r.y=fmaxf(r.y,0.f); r.z=fmaxf(r.z,0.f); r.w=fmaxf(r.w,0.f);
      uint2 p; p.x = bfpack2(r.x,r.y); p.y = bfpack2(r.z,r.w);
      *(uint2*)(hout + (size_t)n*64 + o0) = p;
    }
  }
}

// ------------------------------- pool + MLP -------------------------------

__device__ __forceinline__ int lowerb(const int* __restrict__ b, int n, int key){
  int lo=0, hi=n;
  while (lo<hi){ int mid=(lo+hi)>>1; if (b[mid]<key) lo=mid+1; else hi=mid; }
  return lo;
}

__global__ __launch_bounds__(256) void k_pool(const float* __restrict__ h,
    const int* __restrict__ batch, float* __restrict__ gp, int N){
  __shared__ float red[256];
  int g=blockIdx.x, t=threadIdx.x;
  int start=lowerb(batch,N,g), end=lowerb(batch,N,g+1);
  int c=t&63, p=t>>6;
  float s=0.f;
  for (int n=start+p; n<end; n+=4) s += h[(size_t)n*64+c];
  red[t]=s; __syncthreads();
  if (t<64) gp[g*64+c] = red[c]+red[64+c]+red[128+c]+red[192+c];
}

// one wave per graph: lane l -> hidden j=l&31, half=l>>5
__global__ __launch_bounds__(256) void k_clf(const float* __restrict__ gp,
    const float* __restrict__ cW1, const float* __restrict__ cb1,
    const float* __restrict__ cW2, const float* __restrict__ cb2,
    float* __restrict__ out, int G){
  int lane = threadIdx.x & 63;
  int g = (blockIdx.x*256 + threadIdx.x) >> 6;
  if (g >= G) return;
  int j = lane & 31, half = lane >> 5;
  const float* gv = gp + (size_t)g*64 + half*32;
  const float* Wc = cW1 + half*32*32 + j;
  float s = 0.f;
  #pragma unroll 8
  for (int i=0;i<32;++i) s += gv[i] * Wc[i*32];
  s += __shfl_xor(s, 32);
  s = fmaxf(s + cb1[j], 0.f) * cW2[j];
  s += __shfl_xor(s, 1);  s += __shfl_xor(s, 2);
  s += __shfl_xor(s, 4);  s += __shfl_xor(s, 8);
  s += __shfl_xor(s, 16);
  if (lane == 0) out[g] = s + cb2[0];
}

extern "C" void kernel_launch(void* const* d_in, const int* in_sizes, int n_in,
                              void* d_out, int out_size, void* d_ws, size_t ws_size,
                              hipStream_t stream){
  const float* x     = (const float*)d_in[0];
  const int*   ei    = (const int*)d_in[1];
  const int*   et    = (const int*)d_in[2];
  const int*   batch = (const int*)d_in[3];
  const float* W1    = (const float*)d_in[4];
  const float* root1 = (const float*)d_in[5];
  const float* b1    = (const float*)d_in[6];
  const float* W2    = (const float*)d_in[7];
  const float* root2 = (const float*)d_in[8];
  const float* b2    = (const float*)d_in[9];
  const float* W3    = (const float*)d_in[10];
  const float* root3 = (const float*)d_in[11];
  const float* b3    = (const float*)d_in[12];
  const float* cW1   = (const float*)d_in[13];
  const float* cb1   = (const float*)d_in[14];
  const float* cW2   = (const float*)d_in[15];
  const float* cb2   = (const float*)d_in[16];
  float* out = (float*)d_out;
  (void)n_in; (void)ws_size;

  int N = in_sizes[0]/8;      // 100000
  int E = in_sizes[2];        // 3200000
  int G = out_size;           // 256
  int M = 2*N;

  char* w = (char*)d_ws;
  auto alloc=[&](size_t bytes)->char*{ char* p=w; w += (bytes+255)&~(size_t)255; return p; };
  int*    bhist = (int*)alloc(256*4);
  int*    bbase = (int*)alloc(257*4);
  int*    bcur  = (int*)alloc(256*4);
  int*    ssrc  = (int*)alloc((size_t)E*4);
  int*    deg   = (int*)alloc((size_t)M*4);
  int*    pos   = (int*)alloc((size_t)M*4);
  ushort* h1    = (ushort*)alloc((size_t)N*64*2);
  ushort* snU   = (ushort*)alloc((size_t)N*128*2);
  ushort* h2    = (ushort*)alloc((size_t)N*64*2);  // bk aliases this
  float*  gp    = (float*)alloc((size_t)G*64*4);
  ushort* wt2   = (ushort*)alloc(64*192*2);
  ushort* wt3   = (ushort*)alloc(64*192*2);
  uint*   bk    = (uint*)h2;                       // dead before h2 is written
  float*  sn1   = (float*)snU;                     // [N,16] f32, dead after k_mm24
  float*  hf    = (float*)ssrc;                    // [N,64] f32 spans ssrc+deg+pos+h1, all dead at layer-3 GEMM

  hipMemsetAsync(bhist, 0, 256*4, stream);
  k_wprep<<<1,256,0,stream>>>(W2,root2,wt2);
  k_wprep<<<1,256,0,stream>>>(W3,root3,wt3);
  int nbE = (E + EPB - 1)/EPB;
  k_count<<<nbE,256,0,stream>>>(ei,bhist,E);
  k_bscan<<<1,256,0,stream>>>(bhist,bbase,bcur);
  k_part <<<nbE,256,0,stream>>>(ei,et,bcur,bk,E);
  k_csr  <<<256,256,0,stream>>>(bk,bbase,deg,pos,ssrc,N);

  int gb = (((N+1)/2) + 3) / 4;     // waves = ceil(N/2), 4 waves/block
  int nbk = (N+63)/64;
  // layer 1
  k_gather8 <<<gb,256,0,stream>>>(x,deg,pos,ssrc,sn1,N);
  k_mm24    <<<nbk,256,0,stream>>>(sn1,x,W1,root1,b1,h1,N);
  // layer 2
  k_gather64<<<gb,256,0,stream>>>(h1,deg,pos,ssrc,snU,N);
  k_mm192m<1,1><<<nbk,256,0,stream>>>(snU,h1,wt2,b2,h2,N);
  // layer 3
  k_gather64<<<gb,256,0,stream>>>(h2,deg,pos,ssrc,snU,N);
  k_mm192m<0,0><<<nbk,256,0,stream>>>(snU,h2,wt3,b3,hf,N);
  // pool + head
  k_pool<<<G,256,0,stream>>>(hf,batch,gp,N);
  k_clf<<<(G*64+255)/256,256,0,stream>>>(gp,cW1,cb1,cW2,cb2,out,G);
}

// Round 10
// 469.018 us; speedup vs baseline: 1.2867x; 1.0296x over previous
//
#include <hip/hip_runtime.h>

// ---------------------------------------------------------------------------
// RGCN restructured: aggregate x[src] FIRST (per relation), then one GEMM
//   A = [Sn_rel0 | Sn_rel1 | x_self],  Wcat = [W0; W1; root]
// R4:  CSR build via two-level counting sort (cache-resident random writes).
// R5:  k_clf one wave per graph.
// R9:  R5-structure gathers (indices staged up-front -> continuous feature
//      stream; R6-R8 per-segment staging stalled on vmcnt); MFMA mm192.
// R10: gather64 inner loop split at the (wave-uniform) relation boundary ->
//      pure-rel0 / pure-rel1 packets have NO per-edge select (<=2 masked
//      packets per chunk). CSR build re-bucketed to 128 nodes/bucket
//      (782 blocks, 1 bin/thread in k_csr; was 256 blocks = 1/CU).
// ---------------------------------------------------------------------------

typedef unsigned int uint;
typedef unsigned short ushort;
typedef __attribute__((ext_vector_type(8))) short bf16x8;
typedef __attribute__((ext_vector_type(4))) float f32x4;

#define EPB 8192   // edges per block in count/partition kernels

__device__ __forceinline__ void fma4(float4& a, float s, const float4& w){
  a.x += s*w.x; a.y += s*w.y; a.z += s*w.z; a.w += s*w.w;
}
__device__ __forceinline__ uint bf1(float f){          // f32 -> bf16 (RNE)
  uint u = __float_as_uint(f);
  return (u + 0x7fffu + ((u>>16)&1u)) >> 16;
}
__device__ __forceinline__ uint bfpack2(float lo, float hi){
  return bf1(lo) | (bf1(hi)<<16);
}
__device__ __forceinline__ float4 bf4cvt(uint2 w){
  float4 r;
  r.x = __uint_as_float(w.x<<16);
  r.y = __uint_as_float(w.x & 0xffff0000u);
  r.z = __uint_as_float(w.y<<16);
  r.w = __uint_as_float(w.y & 0xffff0000u);
  return r;
}
__device__ __forceinline__ void addf4(float4& a, const float4& f){
  a.x += f.x; a.y += f.y; a.z += f.z; a.w += f.w;
}
__device__ __forceinline__ void selacc(float4& s, const float4& f, bool take){
  s.x += take ? f.x : 0.f;
  s.y += take ? f.y : 0.f;
  s.z += take ? f.z : 0.f;
  s.w += take ? f.w : 0.f;
}
__device__ __forceinline__ void redf4(float4& a){
  a.x += __shfl_xor(a.x,16); a.x += __shfl_xor(a.x,32);
  a.y += __shfl_xor(a.y,16); a.y += __shfl_xor(a.y,32);
  a.z += __shfl_xor(a.z,16); a.z += __shfl_xor(a.z,32);
  a.w += __shfl_xor(a.w,16); a.w += __shfl_xor(a.w,32);
}

// --------------------- CSR build: two-level counting sort ------------------
// bucket = dst>>7 (128 nodes); NBK = ceil(N/128) buckets.

__global__ __launch_bounds__(256) void k_count(const int* __restrict__ ei,
    int* __restrict__ bhist, int E, int NBK){
  __shared__ int h[800];
  int t = threadIdx.x;
  for (int i=t;i<NBK;i+=256) h[i]=0;
  __syncthreads();
  int base = blockIdx.x*EPB;
  for (int i=t; i<EPB; i+=256){
    int e = base+i;
    if (e < E) atomicAdd(&h[ei[E+e]>>7], 1);
  }
  __syncthreads();
  for (int i=t;i<NBK;i+=256) if (h[i]) atomicAdd(&bhist[i], h[i]);
}

__global__ __launch_bounds__(256) void k_bscan(const int* __restrict__ bhist,
    int* __restrict__ bbase, int* __restrict__ bcur, int NBK, int E){
  __shared__ int lds[256];
  int t = threadIdx.x;
  int v[4]; int s = 0;
  #pragma unroll
  for (int j=0;j<4;++j){ int idx=t*4+j; v[j]=(idx<NBK)?bhist[idx]:0; s+=v[j]; }
  lds[t] = s; __syncthreads();
  for (int off=1; off<256; off<<=1){
    int tmp = (t>=off)? lds[t-off]:0;
    __syncthreads();
    lds[t] += tmp;
    __syncthreads();
  }
  int run = lds[t]-s;
  #pragma unroll
  for (int j=0;j<4;++j){
    int idx=t*4+j;
    if (idx<NBK){ bbase[idx]=run; bcur[idx]=run; }
    run += v[j];
  }
  if (t==255) bbase[NBK] = E;
}

// partition edges into bucket regions as packed (src<<8)|((dst&127)<<1|ty)
__global__ __launch_bounds__(256) void k_part(const int* __restrict__ ei,
    const int* __restrict__ et, int* __restrict__ bcur,
    uint* __restrict__ bk, int E, int NBK){
  __shared__ int h[800];
  __shared__ int cur[800];
  int t = threadIdx.x;
  for (int i=t;i<NBK;i+=256) h[i]=0;
  __syncthreads();
  int base = blockIdx.x*EPB;
  for (int i=t; i<EPB; i+=256){
    int e = base+i;
    if (e < E) atomicAdd(&h[ei[E+e]>>7], 1);
  }
  __syncthreads();
  for (int i=t;i<NBK;i+=256){
    int c = h[i];
    cur[i] = c ? atomicAdd(&bcur[i], c) : 0;
  }
  __syncthreads();
  for (int i=t; i<EPB; i+=256){
    int e = base+i;
    if (e < E){
      int s = ei[e], d = ei[E+e], ty = et[e];
      int p = atomicAdd(&cur[d>>7], 1);
      bk[p] = ((uint)s<<8) | (uint)(((d&127)<<1) | ty);
    }
  }
}

// per-bucket fine sort: 256 bins = 1 bin/thread. deg, pos (segment START),
// ssrc scatter confined to a ~16KB bucket window.
__global__ __launch_bounds__(256) void k_csr(const uint* __restrict__ bk,
    const int* __restrict__ bbase, int* __restrict__ deg,
    int* __restrict__ pos, int* __restrict__ ssrc, int N){
  __shared__ int h[256];
  __shared__ int cur[256];
  __shared__ int ws[256];
  int b = blockIdx.x, t = threadIdx.x;
  int start = bbase[b], end = bbase[b+1];
  h[t]=0;
  __syncthreads();
  for (int i=start+t; i<end; i+=256) atomicAdd(&h[bk[i]&255], 1);
  __syncthreads();
  int c = h[t];
  ws[t] = c; __syncthreads();
  for (int off=1; off<256; off<<=1){
    int tmp = (t>=off)? ws[t-off]:0;
    __syncthreads();
    ws[t] += tmp;
    __syncthreads();
  }
  int p0 = start + ws[t] - c;
  cur[t] = p0;
  int node = (b<<7) + (t>>1);
  if (node < N){ deg[(b<<8)+t] = c; pos[(b<<8)+t] = p0; }
  __syncthreads();
  for (int i=start+t; i<end; i+=256){
    uint w = bk[i];
    int p = atomicAdd(&cur[w & 255], 1);
    ssrc[p] = (int)(w >> 8);
  }
}

// ----------------------- gather (64-ch bf16 features) ---------------------
// R5 staging (indices for BOTH nodes staged at chunk top), inner loop split
// at the wave-uniform relation boundary: pure packets have no per-edge
// select; <=2 masked packets (straddle + tail) per chunk.
__device__ __forceinline__ float4 pktf(const ushort* __restrict__ hp,
    int sv, int e, int eg, int c4){
  int si = __shfl(sv, e+eg);
  uint2 w = *(const uint2*)(hp + (size_t)si*64 + c4*4);
  return bf4cvt(w);
}

// edges [0,bnd) of the staged chunk are rel0, [bnd,tT) rel1.
// j0+idx >= dsplit used only in the masked packets.
__device__ __forceinline__ void gnode(const ushort* __restrict__ hp, int sv,
    int tT, int bnd, int j0, int dsplit, int eg, int c4,
    float4& tot, float4& s1){
  int b0 = bnd & ~3, b1 = (bnd + 3) & ~3;
  int e = 0;
  for (; e+8 <= b0; e += 8){          // pure rel0, 2 loads in flight
    float4 f0 = pktf(hp, sv, e,   eg, c4);
    float4 f1 = pktf(hp, sv, e+4, eg, c4);
    addf4(tot, f0); addf4(tot, f1);
  }
  if (e < b0){ float4 f = pktf(hp, sv, e, eg, c4); addf4(tot, f); e += 4; }
  while (e < tT){
    if (e >= b1 && e+8 <= tT){        // pure rel1, 2 loads in flight
      float4 f0 = pktf(hp, sv, e,   eg, c4);
      float4 f1 = pktf(hp, sv, e+4, eg, c4);
      addf4(tot, f0); addf4(s1, f0);
      addf4(tot, f1); addf4(s1, f1);
      e += 8;
    } else if (e >= b1 && e+4 <= tT){ // pure rel1 single
      float4 f = pktf(hp, sv, e, eg, c4);
      addf4(tot, f); addf4(s1, f);
      e += 4;
    } else {                          // straddle or tail: masked select
      int idx = e + eg;
      int si = __shfl(sv, idx < tT ? idx : 0);
      uint2 w = {0u,0u};
      if (idx < tT) w = *(const uint2*)(hp + (size_t)si*64 + c4*4);
      float4 f = bf4cvt(w);
      addf4(tot, f); selacc(s1, f, (j0+idx) >= dsplit);
      e += 4;
    }
  }
}

__global__ __launch_bounds__(256) void k_gather64(
    const ushort* __restrict__ hp, const int* __restrict__ deg,
    const int* __restrict__ pos, const int* __restrict__ ssrc,
    ushort* __restrict__ sn, int N)
{
  int lane = threadIdx.x & 63;
  int wid  = (blockIdx.x*256 + threadIdx.x) >> 6;
  int c4 = lane & 15, eg = lane >> 4;
  int nA = wid*2, nB = nA+1;
  if (nA >= N) return;
  int d0A = deg[2*nA], d1A = deg[2*nA+1];
  int pA  = pos[2*nA];
  int cA  = d0A + d1A;
  int d0B = 0, d1B = 0, pB = 0, cB = 0;
  if (nB < N){ d0B = deg[2*nB]; d1B = deg[2*nB+1]; pB = pos[2*nB]; cB = d0B+d1B; }

  float4 totA={0,0,0,0}, s1A={0,0,0,0}, totB={0,0,0,0}, s1B={0,0,0,0};
  int jA = 0, jB = 0;
  while (jA < cA || jB < cB){
    int tA = cA - jA; if (tA > 64) tA = 64; if (tA < 0) tA = 0;
    int tB = cB - jB; if (tB > 64) tB = 64; if (tB < 0) tB = 0;
    int svA = (lane < tA) ? ssrc[pA + jA + lane] : 0;
    int svB = (lane < tB) ? ssrc[pB + jB + lane] : 0;
    int bA = d0A - jA; bA = bA < 0 ? 0 : (bA > tA ? tA : bA);
    int bB = d0B - jB; bB = bB < 0 ? 0 : (bB > tB ? tB : bB);
    gnode(hp, svA, tA, bA, jA, d0A, eg, c4, totA, s1A);
    gnode(hp, svB, tB, bB, jB, d0B, eg, c4, totB, s1B);
    jA += tA; jB += tB;
  }
  float4 s0A = {totA.x-s1A.x, totA.y-s1A.y, totA.z-s1A.z, totA.w-s1A.w};
  float4 s0B = {totB.x-s1B.x, totB.y-s1B.y, totB.z-s1B.z, totB.w-s1B.w};
  redf4(s0A); redf4(s1A); redf4(s0B); redf4(s1B);
  float i0A = 1.f/(float)(d0A>1?d0A:1), i1A = 1.f/(float)(d1A>1?d1A:1);
  float i0B = 1.f/(float)(d0B>1?d0B:1), i1B = 1.f/(float)(d1B>1?d1B:1);
  s0A.x*=i0A; s0A.y*=i0A; s0A.z*=i0A; s0A.w*=i0A;
  s1A.x*=i1A; s1A.y*=i1A; s1A.z*=i1A; s1A.w*=i1A;
  s0B.x*=i0B; s0B.y*=i0B; s0B.z*=i0B; s0B.w*=i0B;
  s1B.x*=i1B; s1B.y*=i1B; s1B.z*=i1B; s1B.w*=i1B;
  // lanes 0-15: (A,rel0) 16-31: (A,rel1) 32-47: (B,rel0) 48-63: (B,rel1)
  float4 v = (lane < 32) ? ((lane < 16) ? s0A : s1A)
                         : ((lane < 48) ? s0B : s1B);
  int n   = (lane < 32) ? nA : nB;
  int rel = (lane >> 4) & 1;
  if (n < N){
    uint2 pkt; pkt.x = bfpack2(v.x, v.y); pkt.y = bfpack2(v.z, v.w);
    *(uint2*)(sn + (size_t)n*128 + rel*64 + c4*4) = pkt;
  }
}

// ------------------------ gather (8-ch f32 input x) -----------------------
__global__ __launch_bounds__(256) void k_gather8(
    const float* __restrict__ xp, const int* __restrict__ deg,
    const int* __restrict__ pos, const int* __restrict__ ssrc,
    float* __restrict__ sn1, int N)
{
  int lane = threadIdx.x & 63;
  int wid  = (blockIdx.x*256 + threadIdx.x) >> 6;
  int c = lane & 7, eg = lane >> 3;
  int nA = wid*2, nB = nA+1;
  if (nA >= N) return;
  int d0A = deg[2*nA], d1A = deg[2*nA+1];
  int pA  = pos[2*nA];
  int cA  = d0A + d1A;
  int d0B = 0, d1B = 0, pB = 0, cB = 0;
  if (nB < N){ d0B = deg[2*nB]; d1B = deg[2*nB+1]; pB = pos[2*nB]; cB = d0B+d1B; }

  float totA=0.f, s1A=0.f, totB=0.f, s1B=0.f;
  int jA = 0, jB = 0;
  while (jA < cA || jB < cB){
    int tA = cA - jA; if (tA > 64) tA = 64; if (tA < 0) tA = 0;
    int tB = cB - jB; if (tB > 64) tB = 64; if (tB < 0) tB = 0;
    int svA = (lane < tA) ? ssrc[pA + jA + lane] : 0;
    int svB = (lane < tB) ? ssrc[pB + jB + lane] : 0;
    int mt = tA > tB ? tA : tB;
    for (int e = 0; e < mt; e += 8){
      int idx = e + eg;
      int siA = __shfl(svA, idx), siB = __shfl(svB, idx);
      float vA = 0.f, vB = 0.f;
      if (idx < tA) vA = xp[(size_t)siA*8 + c];
      if (idx < tB) vB = xp[(size_t)siB*8 + c];
      totA += vA;  s1A += ((jA + idx) >= d0A) ? vA : 0.f;
      totB += vB;  s1B += ((jB + idx) >= d0B) ? vB : 0.f;
    }
    jA += tA; jB += tB;
  }
  float s0A = totA - s1A, s0B = totB - s1B;
  #pragma unroll
  for (int off=8; off<64; off<<=1){
    s0A += __shfl_xor(s0A, off); s1A += __shfl_xor(s1A, off);
    s0B += __shfl_xor(s0B, off); s1B += __shfl_xor(s1B, off);
  }
  s0A *= 1.f/(float)(d0A>1?d0A:1);  s1A *= 1.f/(float)(d1A>1?d1A:1);
  s0B *= 1.f/(float)(d0B>1?d0B:1);  s1B *= 1.f/(float)(d1B>1?d1B:1);
  // lanes 0-7:(A,r0) 8-15:(A,r1) 16-23:(B,r0) 24-31:(B,r1)
  if (lane < 32){
    float v = (lane < 16) ? ((lane & 8) ? s1A : s0A)
                          : ((lane & 8) ? s1B : s0B);
    int n = (lane < 16) ? nA : nB;
    if (n < N) sn1[(size_t)n*16 + (lane & 15)] = v;
  }
}

// ------------------- weight pack: Wcat -> bf16 WT[n][k] -------------------
__global__ __launch_bounds__(256) void k_wprep(const float* __restrict__ Wl,
    const float* __restrict__ rootp, ushort* __restrict__ wt){
  int t = threadIdx.x;
  for (int i = t; i < 64*192; i += 256){
    int n = i / 192, k = i - n*192;
    float v = (k < 128) ? Wl[k*64 + n] : rootp[(k-128)*64 + n];
    wt[i] = (ushort)bf1(v);
  }
}

// ----------------- GEMM layers 2/3 (K=192) via MFMA -----------------------
template<int RELU, int OUTBF>
__global__ __launch_bounds__(256) void k_mm192m(
    const ushort* __restrict__ sn,   // [N,128] bf16 (rel0|rel1 means)
    const ushort* __restrict__ hp,   // [N,64]  bf16 self
    const ushort* __restrict__ wt,   // [64,192] bf16 = [Wcat]^T
    const float* __restrict__ bias, void* __restrict__ hout_, int N)
{
  int t = threadIdx.x, lane = t & 63, w = t >> 6;
  int quad = lane >> 4, l15 = lane & 15;
  int nb = blockIdx.x * 64;
  int node = nb + w*16 + l15;
  int ncl = node < N ? node : N-1;
  const ushort* arow_sn = sn + (size_t)ncl*128 + quad*8;
  const ushort* arow_hp = hp + (size_t)ncl*64  + quad*8;

  f32x4 acc0={0,0,0,0}, acc1={0,0,0,0}, acc2={0,0,0,0}, acc3={0,0,0,0};
  #pragma unroll
  for (int ks = 0; ks < 6; ++ks){
    bf16x8 a = (ks < 4) ? *(const bf16x8*)(arow_sn + ks*32)
                        : *(const bf16x8*)(arow_hp + (ks-4)*32);
    const ushort* wk = wt + (size_t)l15*192 + ks*32 + quad*8;
    bf16x8 b0 = *(const bf16x8*)(wk);
    bf16x8 b1 = *(const bf16x8*)(wk + 16*192);
    bf16x8 b2 = *(const bf16x8*)(wk + 32*192);
    bf16x8 b3 = *(const bf16x8*)(wk + 48*192);
    acc0 = __builtin_amdgcn_mfma_f32_16x16x32_bf16(a, b0, acc0, 0,0,0);
    acc1 = __builtin_amdgcn_mfma_f32_16x16x32_bf16(a, b1, acc1, 0,0,0);
    acc2 = __builtin_amdgcn_mfma_f32_16x16x32_bf16(a, b2, acc2, 0,0,0);
    acc3 = __builtin_amdgcn_mfma_f32_16x16x32_bf16(a, b3, acc3, 0,0,0);
  }
  f32x4 accs[4] = {acc0, acc1, acc2, acc3};
  #pragma unroll
  for (int tt = 0; tt < 4; ++tt){
    int n = tt*16 + l15;                 // output channel
    float bv = bias[n];
    #pragma unroll
    for (int i = 0; i < 4; ++i){
      int nd = nb + w*16 + quad*4 + i;   // node (D row)
      if (nd < N){
        float v = accs[tt][i] + bv;
        if (RELU) v = fmaxf(v, 0.f);
        if (OUTBF) ((ushort*)hout_)[(size_t)nd*64 + n] = (ushort)bf1(v);
        else       ((float*)hout_)[(size_t)nd*64 + n] = v;
      }
    }
  }
}

// -------------------------- GEMM layer 1 (K=24) ---------------------------
__global__ __launch_bounds__(256) void k_mm24(
    const float* __restrict__ sn1,   // [N,16] f32
    const float* __restrict__ xp,    // [N,8] f32 self
    const float* __restrict__ Wl,    // [16,64]
    const float* __restrict__ rootp, // [8,64]
    const float* __restrict__ bias, ushort* __restrict__ hout, int N)
{
  __shared__ float A[64*25];
  int t = threadIdx.x;
  int nb = blockIdx.x*64;
  #pragma unroll
  for (int k=0;k<4;++k){
    int q = k*256 + t;
    int nl = q>>4, c = q&15;
    int n = nb + nl;
    A[nl*25 + c] = (n < N) ? sn1[(size_t)n*16 + c] : 0.f;
  }
  #pragma unroll
  for (int k=0;k<2;++k){
    int q = k*256 + t;
    int nl = q>>3, c = q&7;
    int n = nb + nl;
    A[nl*25 + 16 + c] = (n < N) ? xp[(size_t)n*8 + c] : 0.f;
  }
  __syncthreads();
  int o0=(t&15)*4, r0=(t>>4)*4;
  float4 b4 = *(const float4*)(bias+o0);
  float4 a0=b4,a1=b4,a2=b4,a3=b4;
  const float* Ab=&A[r0*25];
  #pragma unroll
  for (int i=0;i<16;++i){
    float4 w=*(const float4*)(Wl+i*64+o0);
    fma4(a0,Ab[i],w); fma4(a1,Ab[25+i],w); fma4(a2,Ab[50+i],w); fma4(a3,Ab[75+i],w);
  }
  #pragma unroll
  for (int i=0;i<8;++i){
    float4 w=*(const float4*)(rootp+i*64+o0);
    fma4(a0,Ab[16+i],w); fma4(a1,Ab[41+i],w); fma4(a2,Ab[66+i],w); fma4(a3,Ab[91+i],w);
  }
  float4 accs[4]={a0,a1,a2,a3};
  #pragma unroll
  for (int q=0;q<4;++q){
    int n = nb + r0 + q;
    if (n < N){
      float4 r = accs[q];
      r.x=fmaxf(r.x,0.f); r.y=fmaxf(r.y,0.f); r.z=fmaxf(r.z,0.f); r.w=fmaxf(r.w,0.f);
      uint2 p; p.x = bfpack2(r.x,r.y); p.y = bfpack2(r.z,r.w);
      *(uint2*)(hout + (size_t)n*64 + o0) = p;
    }
  }
}

// ------------------------------- pool + MLP -------------------------------

__device__ __forceinline__ int lowerb(const int* __restrict__ b, int n, int key){
  int lo=0, hi=n;
  while (lo<hi){ int mid=(lo+hi)>>1; if (b[mid]<key) lo=mid+1; else hi=mid; }
  return lo;
}

__global__ __launch_bounds__(256) void k_pool(const float* __restrict__ h,
    const int* __restrict__ batch, float* __restrict__ gp, int N){
  __shared__ float red[256];
  int g=blockIdx.x, t=threadIdx.x;
  int start=lowerb(batch,N,g), end=lowerb(batch,N,g+1);
  int c=t&63, p=t>>6;
  float s=0.f;
  for (int n=start+p; n<end; n+=4) s += h[(size_t)n*64+c];
  red[t]=s; __syncthreads();
  if (t<64) gp[g*64+c] = red[c]+red[64+c]+red[128+c]+red[192+c];
}

// one wave per graph: lane l -> hidden j=l&31, half=l>>5
__global__ __launch_bounds__(256) void k_clf(const float* __restrict__ gp,
    const float* __restrict__ cW1, const float* __restrict__ cb1,
    const float* __restrict__ cW2, const float* __restrict__ cb2,
    float* __restrict__ out, int G){
  int lane = threadIdx.x & 63;
  int g = (blockIdx.x*256 + threadIdx.x) >> 6;
  if (g >= G) return;
  int j = lane & 31, half = lane >> 5;
  const float* gv = gp + (size_t)g*64 + half*32;
  const float* Wc = cW1 + half*32*32 + j;
  float s = 0.f;
  #pragma unroll 8
  for (int i=0;i<32;++i) s += gv[i] * Wc[i*32];
  s += __shfl_xor(s, 32);
  s = fmaxf(s + cb1[j], 0.f) * cW2[j];
  s += __shfl_xor(s, 1);  s += __shfl_xor(s, 2);
  s += __shfl_xor(s, 4);  s += __shfl_xor(s, 8);
  s += __shfl_xor(s, 16);
  if (lane == 0) out[g] = s + cb2[0];
}

extern "C" void kernel_launch(void* const* d_in, const int* in_sizes, int n_in,
                              void* d_out, int out_size, void* d_ws, size_t ws_size,
                              hipStream_t stream){
  const float* x     = (const float*)d_in[0];
  const int*   ei    = (const int*)d_in[1];
  const int*   et    = (const int*)d_in[2];
  const int*   batch = (const int*)d_in[3];
  const float* W1    = (const float*)d_in[4];
  const float* root1 = (const float*)d_in[5];
  const float* b1    = (const float*)d_in[6];
  const float* W2    = (const float*)d_in[7];
  const float* root2 = (const float*)d_in[8];
  const float* b2    = (const float*)d_in[9];
  const float* W3    = (const float*)d_in[10];
  const float* root3 = (const float*)d_in[11];
  const float* b3    = (const float*)d_in[12];
  const float* cW1   = (const float*)d_in[13];
  const float* cb1   = (const float*)d_in[14];
  const float* cW2   = (const float*)d_in[15];
  const float* cb2   = (const float*)d_in[16];
  float* out = (float*)d_out;
  (void)n_in; (void)ws_size;

  int N = in_sizes[0]/8;      // 100000
  int E = in_sizes[2];        // 3200000
  int G = out_size;           // 256
  int M = 2*N;
  int NBK = (N + 127) >> 7;   // 782 buckets of 128 nodes

  char* w = (char*)d_ws;
  auto alloc=[&](size_t bytes)->char*{ char* p=w; w += (bytes+255)&~(size_t)255; return p; };
  int*    bhist = (int*)alloc(1024*4);
  int*    bbase = (int*)alloc(1025*4);
  int*    bcur  = (int*)alloc(1024*4);
  int*    ssrc  = (int*)alloc((size_t)E*4);
  int*    deg   = (int*)alloc((size_t)M*4);
  int*    pos   = (int*)alloc((size_t)M*4);
  ushort* h1    = (ushort*)alloc((size_t)N*64*2);
  ushort* snU   = (ushort*)alloc((size_t)N*128*2);
  ushort* h2    = (ushort*)alloc((size_t)N*64*2);  // bk aliases this
  float*  gp    = (float*)alloc((size_t)G*64*4);
  ushort* wt2   = (ushort*)alloc(64*192*2);
  ushort* wt3   = (ushort*)alloc(64*192*2);
  uint*   bk    = (uint*)h2;                       // dead before h2 is written
  float*  sn1   = (float*)snU;                     // [N,16] f32, dead after k_mm24
  float*  hf    = (float*)ssrc;                    // [N,64] f32 spans ssrc+deg+pos+h1, all dead at layer-3 GEMM

  hipMemsetAsync(bhist, 0, 1024*4, stream);
  k_wprep<<<1,256,0,stream>>>(W2,root2,wt2);
  k_wprep<<<1,256,0,stream>>>(W3,root3,wt3);
  int nbE = (E + EPB - 1)/EPB;
  k_count<<<nbE,256,0,stream>>>(ei,bhist,E,NBK);
  k_bscan<<<1,256,0,stream>>>(bhist,bbase,bcur,NBK,E);
  k_part <<<nbE,256,0,stream>>>(ei,et,bcur,bk,E,NBK);
  k_csr  <<<NBK,256,0,stream>>>(bk,bbase,deg,pos,ssrc,N);

  int gb = (((N+1)/2) + 3) / 4;     // waves = ceil(N/2), 4 waves/block
  int nbk = (N+63)/64;
  // layer 1
  k_gather8 <<<gb,256,0,stream>>>(x,deg,pos,ssrc,sn1,N);
  k_mm24    <<<nbk,256,0,stream>>>(sn1,x,W1,root1,b1,h1,N);
  // layer 2
  k_gather64<<<gb,256,0,stream>>>(h1,deg,pos,ssrc,snU,N);
  k_mm192m<1,1><<<nbk,256,0,stream>>>(snU,h1,wt2,b2,h2,N);
  // layer 3
  k_gather64<<<gb,256,0,stream>>>(h2,deg,pos,ssrc,snU,N);
  k_mm192m<0,0><<<nbk,256,0,stream>>>(snU,h2,wt3,b3,hf,N);
  // pool + head
  k_pool<<<G,256,0,stream>>>(hf,batch,gp,N);
  k_clf<<<(G*64+255)/256,256,0,stream>>>(gp,cW1,cb1,cW2,cb2,out,G);
}